// Round 1
// baseline (507.799 us; speedup 1.0000x reference)
//
#include <hip/hip_runtime.h>
#include <math.h>

#define TPB 256

// Problem constants
constexpr int Bc = 16, Tc = 1536, Vc = 64;
constexpr int F2c = 32;            // H*FO = 4*8
constexpr int T2c = 192;           // T / P1
constexpr float EPSc = 1e-5f;
constexpr float NSLOPE = 0.2f;

// Workspace layout (float offsets)
constexpr int OW_WEFF = 0;                 // [32 k][32 f2]
constexpr int OW_CHL  = 1024;              // [32]
constexpr int OW_A2   = 1056;              // [32]
constexpr int OW_C2   = 1088;              // [32] (gat bias folded in)
constexpr int OW_A3   = 1120;              // [32]
constexpr int OW_C3   = 1152;              // [32]
constexpr int OW_W3T  = 1184;              // [16 k][32 f2i][32 f2o]
constexpr int OW_CSRO = OW_W3T + 16384;    // 65 ints
constexpr int OW_CSRS = OW_CSRO + 65;      // 320 ints
constexpr int OW_G    = 17984;             // [B][T][32]  = 786432 floats
constexpr int OW_P    = OW_G + Bc*Tc*F2c;  // [B][192][32] = 98304 floats

// ---------------------------------------------------------------------------
// Prep: fold bn1+gatW+conv1 -> weff/const; fold bn affines; transpose conv3_w;
// build CSR (incoming edges per dst) from edge_index.
// ---------------------------------------------------------------------------
__global__ void prep_kernel(const float* __restrict__ c1w,
                            const float* __restrict__ g1, const float* __restrict__ b1,
                            const float* __restrict__ m1, const float* __restrict__ v1,
                            const float* __restrict__ W,  const float* __restrict__ bias,
                            const float* __restrict__ g2, const float* __restrict__ b2,
                            const float* __restrict__ m2, const float* __restrict__ v2,
                            const float* __restrict__ w3,
                            const float* __restrict__ g3, const float* __restrict__ b3,
                            const float* __restrict__ m3, const float* __restrict__ v3,
                            const int* __restrict__ ei, int ne, float* __restrict__ ws)
{
    __shared__ int cur[64];
    const int tid = threadIdx.x;

    // weff[k*32+f2] = sum_f a1[f]*W[f,f2]*w1[f,k]
    for (int idx = tid; idx < 1024; idx += TPB) {
        int k = idx >> 5, f2 = idx & 31;
        float s = 0.f;
        for (int f = 0; f < 16; f++) {
            float a1 = g1[f] * rsqrtf(v1[f] + EPSc);
            s += a1 * W[f * 32 + f2] * c1w[f * 32 + k];
        }
        ws[OW_WEFF + idx] = s;
    }
    for (int f2 = tid; f2 < 32; f2 += TPB) {
        float s = 0.f;
        for (int f = 0; f < 16; f++) {
            float a1 = g1[f] * rsqrtf(v1[f] + EPSc);
            float c1 = b1[f] - a1 * m1[f];
            s += c1 * W[f * 32 + f2];
        }
        ws[OW_CHL + f2] = s;
        float a2 = g2[f2] * rsqrtf(v2[f2] + EPSc);
        ws[OW_A2 + f2] = a2;
        ws[OW_C2 + f2] = b2[f2] + a2 * (bias[f2] - m2[f2]);   // gat bias folded
        float a3 = g3[f2] * rsqrtf(v3[f2] + EPSc);
        ws[OW_A3 + f2] = a3;
        ws[OW_C3 + f2] = b3[f2] - a3 * m3[f2];
    }
    // w3t[(k*32+f2i)*32+f2o] = w3[f2o][f2i][k]
    for (int idx = tid; idx < 16384; idx += TPB) {
        int f2o = idx & 31, r = idx >> 5;
        int f2i = r & 31, k = r >> 5;
        ws[OW_W3T + idx] = w3[(f2o * 32 + f2i) * 16 + k];
    }
    if (tid == 0) {
        int* co = (int*)(ws + OW_CSRO);
        int* cs = (int*)(ws + OW_CSRS);
        for (int d = 0; d < 64; d++) cur[d] = 0;
        for (int e = 0; e < ne; e++) cur[ei[ne + e]]++;
        int run = 0;
        for (int d = 0; d < 64; d++) { int dg = cur[d]; co[d] = run; cur[d] = run; run += dg; }
        co[64] = run;
        for (int e = 0; e < ne; e++) { int d = ei[ne + e]; cs[cur[d]++] = ei[e]; }
    }
}

// ---------------------------------------------------------------------------
// Main fused kernel: conv1+bn1+GAT-linear + attention + mean over nodes.
// One wave per (b,t) graph; lane = node. Block = 4 waves covering 16 t.
// ---------------------------------------------------------------------------
__global__ __launch_bounds__(TPB) void gat_kernel(const float* __restrict__ x,
                                                  const float* __restrict__ asrc,
                                                  const float* __restrict__ adst,
                                                  const float* __restrict__ wf,
                                                  const float* __restrict__ chl,
                                                  const int* __restrict__ co,
                                                  const int* __restrict__ cs,
                                                  float* __restrict__ gout)
{
    __shared__ float xt[64 * 49];        // x tile, 47 cols used, stride 49 (2-way free)
    __shared__ float hl[4][64 * 33];     // per-wave hlin rows, stride 33
    __shared__ float esd[4][64 * 9];     // per-wave es[4] rows, stride 9
    __shared__ int soff[65];
    __shared__ int ssrc[320];

    const int tid  = threadIdx.x;
    const int b    = blockIdx.x / 96;
    const int tile = blockIdx.x % 96;
    const int t0   = tile * 16;

    // Stage x tile [v=0..63][t0-15 .. t0+31] with zero pad
    for (int idx = tid; idx < 64 * 48; idx += TPB) {
        int v = idx / 48, j = idx % 48;
        if (j < 47) {
            int t = t0 - 15 + j;
            xt[v * 49 + j] = (t >= 0 && t < Tc) ? x[(b * 64 + v) * Tc + t] : 0.f;
        }
    }
    for (int idx = tid; idx < 65;  idx += TPB) soff[idx] = co[idx];
    for (int idx = tid; idx < 320; idx += TPB) ssrc[idx] = cs[idx];
    __syncthreads();

    const int wid = tid >> 6, lane = tid & 63;
    float* myhl  = hl[wid];
    float* myesd = esd[wid];

    for (int g = 0; g < 4; g++) {
        const int tloc = wid * 4 + g;
        const int t    = t0 + tloc;

        // fused conv1+bn1+linear: hlin[lane][f2]
        float acc[32];
        #pragma unroll
        for (int f2 = 0; f2 < 32; f2++) acc[f2] = chl[f2];
        #pragma unroll
        for (int k = 0; k < 32; k++) {
            float xk = xt[lane * 49 + tloc + k];
            #pragma unroll
            for (int f2 = 0; f2 < 32; f2++)
                acc[f2] = fmaf(xk, wf[k * 32 + f2], acc[f2]);
        }

        // attention logits pieces
        float es[4], ed[4];
        #pragma unroll
        for (int h = 0; h < 4; h++) {
            float s1 = 0.f, s2 = 0.f;
            #pragma unroll
            for (int o = 0; o < 8; o++) {
                s1 = fmaf(acc[h * 8 + o], asrc[h * 8 + o], s1);
                s2 = fmaf(acc[h * 8 + o], adst[h * 8 + o], s2);
            }
            es[h] = s1; ed[h] = s2;
        }
        #pragma unroll
        for (int f2 = 0; f2 < 32; f2++) myhl[lane * 33 + f2] = acc[f2];
        #pragma unroll
        for (int h = 0; h < 4; h++) myesd[lane * 9 + h] = es[h];
        __syncthreads();

        // lane = dst node: softmax over incoming edges + weighted aggregation
        const int beg = soff[lane], end = soff[lane + 1];
        float mx[4] = { -1e30f, -1e30f, -1e30f, -1e30f };
        for (int e = beg; e < end; e++) {
            int sn = ssrc[e];
            #pragma unroll
            for (int h = 0; h < 4; h++) {
                float ev = myesd[sn * 9 + h] + ed[h];
                ev = ev > 0.f ? ev : NSLOPE * ev;
                mx[h] = fmaxf(mx[h], ev);
            }
        }
        float den[4] = { 0.f, 0.f, 0.f, 0.f };
        float out[32];
        #pragma unroll
        for (int f2 = 0; f2 < 32; f2++) out[f2] = 0.f;
        for (int e = beg; e < end; e++) {
            int sn = ssrc[e];
            float ex[4];
            #pragma unroll
            for (int h = 0; h < 4; h++) {
                float ev = myesd[sn * 9 + h] + ed[h];
                ev = ev > 0.f ? ev : NSLOPE * ev;
                ex[h] = __expf(ev - mx[h]);
                den[h] += ex[h];
            }
            #pragma unroll
            for (int f2 = 0; f2 < 32; f2++)
                out[f2] = fmaf(ex[f2 >> 3], myhl[sn * 33 + f2], out[f2]);
        }
        float rden[4];
        #pragma unroll
        for (int h = 0; h < 4; h++) rden[h] = 1.f / den[h];
        #pragma unroll
        for (int f2 = 0; f2 < 32; f2++) out[f2] *= rden[f2 >> 3];
        __syncthreads();

        // mean over nodes: stash out rows, split-reduce
        #pragma unroll
        for (int f2 = 0; f2 < 32; f2++) myhl[lane * 33 + f2] = out[f2];
        __syncthreads();
        int f2r = lane & 31, half = lane >> 5;
        float sum = 0.f;
        #pragma unroll
        for (int d = 0; d < 32; d++) sum += myhl[(d + 32 * half) * 33 + f2r];
        sum += __shfl_down(sum, 32);
        if (lane < 32) gout[(b * Tc + t) * 32 + f2r] = sum * (1.f / 64.f);
        __syncthreads();
    }
}

// ---------------------------------------------------------------------------
// bn2 + elu + avgpool(8):  g[B,T,32] -> p[B,192,32]
// ---------------------------------------------------------------------------
__global__ void pool2a_kernel(const float* __restrict__ a2, const float* __restrict__ c2,
                              const float* __restrict__ gp, float* __restrict__ pp)
{
    int gid = blockIdx.x * TPB + threadIdx.x;    // [0, 16*192*32)
    int f2 = gid & 31;
    int rem = gid >> 5;                          // b*192 + to
    const float a = a2[f2], c = c2[f2];
    int base = rem * 8;                          // = b*1536 + to*8
    float s = 0.f;
    #pragma unroll
    for (int j = 0; j < 8; j++) {
        float gv = gp[(base + j) * 32 + f2];
        float y = fmaf(a, gv, c);
        s += y > 0.f ? y : __expf(y) - 1.f;
    }
    pp[gid] = s * 0.125f;
}

// ---------------------------------------------------------------------------
// conv3(K=16,'same') + bn3 + elu + avgpool(4): p[B,192,32] -> out[B,32,48]
// Block = (b, 48-to chunk). 256 thr = 32 f2o x 8 groups of 6 to.
// ---------------------------------------------------------------------------
__global__ __launch_bounds__(TPB) void conv3_kernel(const float* __restrict__ pp,
                                                    const float* __restrict__ w3t,
                                                    const float* __restrict__ a3p,
                                                    const float* __restrict__ c3p,
                                                    float* __restrict__ outp)
{
    __shared__ float pl[63 * 32];
    __shared__ float q[48 * 32];
    const int tid = threadIdx.x;
    const int b = blockIdx.x >> 2, cc = blockIdx.x & 3;

    for (int idx = tid; idx < 63 * 32; idx += TPB) {
        int r = idx >> 5, f2 = idx & 31;
        int tog = cc * 48 - 7 + r;
        pl[idx] = (tog >= 0 && tog < T2c) ? pp[(b * T2c + tog) * 32 + f2] : 0.f;
    }
    __syncthreads();

    const int f2o = tid & 31, grp = tid >> 5;
    const int tb = grp * 6;
    float acc[6] = { 0.f, 0.f, 0.f, 0.f, 0.f, 0.f };
    for (int f2i = 0; f2i < 32; f2i++) {
        float seg[21];
        #pragma unroll
        for (int r = 0; r < 21; r++) seg[r] = pl[(tb + r) * 32 + f2i];
        #pragma unroll
        for (int k = 0; k < 16; k++) {
            float wv = w3t[(k * 32 + f2i) * 32 + f2o];
            #pragma unroll
            for (int j = 0; j < 6; j++)
                acc[j] = fmaf(seg[j + k], wv, acc[j]);
        }
    }
    const float a3 = a3p[f2o], c3 = c3p[f2o];
    #pragma unroll
    for (int j = 0; j < 6; j++) {
        float y = fmaf(a3, acc[j], c3);
        y = y > 0.f ? y : __expf(y) - 1.f;
        q[(tb + j) * 32 + f2o] = y;
    }
    __syncthreads();
    for (int idx = tid; idx < 12 * 32; idx += TPB) {
        int t4 = idx >> 5, f2 = idx & 31;
        int r0 = t4 * 4;
        float s = q[r0 * 32 + f2] + q[(r0 + 1) * 32 + f2] +
                  q[(r0 + 2) * 32 + f2] + q[(r0 + 3) * 32 + f2];
        outp[(b * 32 + f2) * 48 + cc * 12 + t4] = s * 0.25f;
    }
}

// ---------------------------------------------------------------------------
extern "C" void kernel_launch(void* const* d_in, const int* in_sizes, int n_in,
                              void* d_out, int out_size, void* d_ws, size_t ws_size,
                              hipStream_t stream)
{
    const float* x    = (const float*)d_in[0];
    const float* c1w  = (const float*)d_in[1];
    const float* g1   = (const float*)d_in[2];
    const float* b1   = (const float*)d_in[3];
    const float* m1   = (const float*)d_in[4];
    const float* v1   = (const float*)d_in[5];
    const float* W    = (const float*)d_in[6];
    const float* asrc = (const float*)d_in[7];
    const float* adst = (const float*)d_in[8];
    const float* bias = (const float*)d_in[9];
    const float* g2   = (const float*)d_in[10];
    const float* b2   = (const float*)d_in[11];
    const float* m2   = (const float*)d_in[12];
    const float* v2   = (const float*)d_in[13];
    const float* w3   = (const float*)d_in[14];
    const float* g3   = (const float*)d_in[15];
    const float* b3   = (const float*)d_in[16];
    const float* m3   = (const float*)d_in[17];
    const float* v3   = (const float*)d_in[18];
    const int*   ei   = (const int*)d_in[19];
    const int    ne   = in_sizes[19] / 2;

    float* ws = (float*)d_ws;

    prep_kernel<<<1, TPB, 0, stream>>>(c1w, g1, b1, m1, v1, W, bias,
                                       g2, b2, m2, v2, w3, g3, b3, m3, v3, ei, ne, ws);

    gat_kernel<<<Bc * 96, TPB, 0, stream>>>(x, asrc, adst,
                                            ws + OW_WEFF, ws + OW_CHL,
                                            (const int*)(ws + OW_CSRO),
                                            (const int*)(ws + OW_CSRS),
                                            ws + OW_G);

    pool2a_kernel<<<(Bc * T2c * F2c) / TPB, TPB, 0, stream>>>(ws + OW_A2, ws + OW_C2,
                                                              ws + OW_G, ws + OW_P);

    conv3_kernel<<<Bc * 4, TPB, 0, stream>>>(ws + OW_P, ws + OW_W3T,
                                             ws + OW_A3, ws + OW_C3, (float*)d_out);
}

// Round 2
// 502.785 us; speedup vs baseline: 1.0100x; 1.0100x over previous
//
#include <hip/hip_runtime.h>
#include <math.h>

#define TPB 256

// Problem constants
constexpr int Bc = 16, Tc = 1536;
constexpr int F2c = 32;            // H*FO = 4*8
constexpr int T2c = 192;           // T / P1
constexpr float EPSc = 1e-5f;
constexpr float NSLOPE = 0.2f;

// Workspace layout (float offsets)
constexpr int OW_WEFF = 0;                 // [32 k][32 f2]
constexpr int OW_CHL  = 1024;              // [32]
constexpr int OW_A2   = 1056;              // [32]
constexpr int OW_C2   = 1088;              // [32] (gat bias folded in)
constexpr int OW_A3   = 1120;              // [32]
constexpr int OW_C3   = 1152;              // [32]
constexpr int OW_W3T  = 1184;              // [16 k][32 f2i][32 f2o]
constexpr int OW_CSRO = OW_W3T + 16384;    // 65 ints
constexpr int OW_CSRS = OW_CSRO + 65;      // 320 ints
constexpr int OW_G    = 17984;             // [B][T][32]  = 786432 floats
constexpr int OW_P    = OW_G + Bc*Tc*F2c;  // [B][192][32] = 98304 floats

// ---------------------------------------------------------------------------
// Prep: fold bn1+gatW+conv1 -> weff/const; fold bn affines; transpose conv3_w;
// build CSR (incoming edges per dst) from edge_index — parallel via LDS atomics.
// ---------------------------------------------------------------------------
__global__ void prep_kernel(const float* __restrict__ c1w,
                            const float* __restrict__ g1, const float* __restrict__ b1,
                            const float* __restrict__ m1, const float* __restrict__ v1,
                            const float* __restrict__ W,  const float* __restrict__ bias,
                            const float* __restrict__ g2, const float* __restrict__ b2,
                            const float* __restrict__ m2, const float* __restrict__ v2,
                            const float* __restrict__ w3,
                            const float* __restrict__ g3, const float* __restrict__ b3,
                            const float* __restrict__ m3, const float* __restrict__ v3,
                            const int* __restrict__ ei, int ne, float* __restrict__ ws)
{
    __shared__ int cnt[64];
    const int tid = threadIdx.x;

    // weff[k*32+f2] = sum_f a1[f]*W[f,f2]*w1[f,k]
    for (int idx = tid; idx < 1024; idx += TPB) {
        int k = idx >> 5, f2 = idx & 31;
        float s = 0.f;
        for (int f = 0; f < 16; f++) {
            float a1 = g1[f] * rsqrtf(v1[f] + EPSc);
            s += a1 * W[f * 32 + f2] * c1w[f * 32 + k];
        }
        ws[OW_WEFF + idx] = s;
    }
    for (int f2 = tid; f2 < 32; f2 += TPB) {
        float s = 0.f;
        for (int f = 0; f < 16; f++) {
            float a1 = g1[f] * rsqrtf(v1[f] + EPSc);
            float c1 = b1[f] - a1 * m1[f];
            s += c1 * W[f * 32 + f2];
        }
        ws[OW_CHL + f2] = s;
        float a2 = g2[f2] * rsqrtf(v2[f2] + EPSc);
        ws[OW_A2 + f2] = a2;
        ws[OW_C2 + f2] = b2[f2] + a2 * (bias[f2] - m2[f2]);   // gat bias folded
        float a3 = g3[f2] * rsqrtf(v3[f2] + EPSc);
        ws[OW_A3 + f2] = a3;
        ws[OW_C3 + f2] = b3[f2] - a3 * m3[f2];
    }
    // w3t[(k*32+f2i)*32+f2o] = w3[f2o][f2i][k]
    for (int idx = tid; idx < 16384; idx += TPB) {
        int f2o = idx & 31, r = idx >> 5;
        int f2i = r & 31, k = r >> 5;
        ws[OW_W3T + idx] = w3[(f2o * 32 + f2i) * 16 + k];
    }

    // CSR build: histogram -> prefix -> scatter (LDS atomics, no serial global chain)
    int* co = (int*)(ws + OW_CSRO);
    int* cs = (int*)(ws + OW_CSRS);
    if (tid < 64) cnt[tid] = 0;
    __syncthreads();
    for (int e = tid; e < ne; e += TPB) atomicAdd(&cnt[ei[ne + e]], 1);
    __syncthreads();
    if (tid == 0) {
        int run = 0;
        for (int d = 0; d < 64; d++) { int c = cnt[d]; co[d] = run; cnt[d] = run; run += c; }
        co[64] = run;
    }
    __syncthreads();
    for (int e = tid; e < ne; e += TPB) {
        int d = ei[ne + e];
        int pos = atomicAdd(&cnt[d], 1);
        cs[pos] = ei[e];
    }
}

// ---------------------------------------------------------------------------
// Main fused kernel: conv1+bn1+GAT-linear + attention + mean over nodes.
// One wave per (b,t); lane = node. Key identity: mean over dst collapses the
// per-dst aggregation:  g[t,f2] = sum_v wbar[v,h(f2)] * h[v,f2], where
// wbar[v,h] = (1/64) * sum_dst alpha[dst,v,h].  h stays in registers; only
// es (64x4) and wbar (64x4) go through per-wave LDS. No in-loop barriers.
// ---------------------------------------------------------------------------
__global__ __launch_bounds__(TPB) void gat_kernel(const float* __restrict__ x,
                                                  const float* __restrict__ asrc,
                                                  const float* __restrict__ adst,
                                                  const float* __restrict__ wf,
                                                  const float* __restrict__ chl,
                                                  const int* __restrict__ co,
                                                  const int* __restrict__ cs,
                                                  float* __restrict__ gout)
{
    __shared__ float xt[64 * 49];        // x tile, 47 cols used, stride 49 (2-way free)
    __shared__ float es_s[4][64 * 8];    // per-wave es[h] rows, stride 8 (b128-aligned)
    __shared__ float w_s[4][64 * 8];     // per-wave wbar accumulation
    __shared__ int soff[65];
    __shared__ int ssrc[320];

    const int tid  = threadIdx.x;
    const int b    = blockIdx.x / 96;
    const int t0   = (blockIdx.x % 96) * 16;

    // Stage x tile [v=0..63][t0-15 .. t0+31] with zero pad
    for (int idx = tid; idx < 64 * 48; idx += TPB) {
        int v = idx / 48, j = idx % 48;
        if (j < 47) {
            int t = t0 - 15 + j;
            xt[v * 49 + j] = (t >= 0 && t < Tc) ? x[(b * 64 + v) * Tc + t] : 0.f;
        }
    }
    if (tid < 65) soff[tid] = co[tid];
    for (int idx = tid; idx < 320; idx += TPB) ssrc[idx] = cs[idx];
    __syncthreads();

    const int wid = tid >> 6, lane = tid & 63;
    float* mes = es_s[wid];
    float* mw  = w_s[wid];
    const int beg = soff[lane], end = soff[lane + 1];

    for (int g = 0; g < 4; g++) {
        const int tloc = wid * 4 + g;
        const int t    = t0 + tloc;

        // fused conv1+bn1+linear: h[lane][f2] in registers
        float acc[32];
        #pragma unroll
        for (int f2 = 0; f2 < 32; f2++) acc[f2] = chl[f2];
        #pragma unroll
        for (int k = 0; k < 32; k++) {
            float xk = xt[lane * 49 + tloc + k];
            #pragma unroll
            for (int f2 = 0; f2 < 32; f2++)
                acc[f2] = fmaf(xk, wf[k * 32 + f2], acc[f2]);
        }

        // attention logit pieces
        float es[4], ed[4];
        #pragma unroll
        for (int h = 0; h < 4; h++) {
            float s1 = 0.f, s2 = 0.f;
            #pragma unroll
            for (int o = 0; o < 8; o++) {
                s1 = fmaf(acc[h * 8 + o], asrc[h * 8 + o], s1);
                s2 = fmaf(acc[h * 8 + o], adst[h * 8 + o], s2);
            }
            es[h] = s1; ed[h] = s2;
        }
        #pragma unroll
        for (int h = 0; h < 4; h++) { mes[lane * 8 + h] = es[h]; mw[lane * 8 + h] = 0.f; }

        // pass A (lane = dst): softmax denominator over incoming edges.
        // No max-subtraction: |logit| is O(10), exp stays well inside fp32;
        // alpha = ex/den is identical to the max-shifted ratio.
        float den[4] = { 0.f, 0.f, 0.f, 0.f };
        for (int e = beg; e < end; e++) {
            int sn = ssrc[e];
            #pragma unroll
            for (int h = 0; h < 4; h++) {
                float ev = mes[sn * 8 + h] + ed[h];
                ev = ev > 0.f ? ev : NSLOPE * ev;
                den[h] += __expf(ev);
            }
        }
        float rden[4];
        #pragma unroll
        for (int h = 0; h < 4; h++) rden[h] = 1.f / den[h];

        // pass B: scatter alpha into wbar[src]
        for (int e = beg; e < end; e++) {
            int sn = ssrc[e];
            #pragma unroll
            for (int h = 0; h < 4; h++) {
                float ev = mes[sn * 8 + h] + ed[h];
                ev = ev > 0.f ? ev : NSLOPE * ev;
                atomicAdd(&mw[sn * 8 + h], __expf(ev) * rden[h]);
            }
        }
        // same-wave DS ops complete in order; force drain before readback
        __asm__ volatile("s_waitcnt lgkmcnt(0)" ::: "memory");

        float w4[4];
        #pragma unroll
        for (int h = 0; h < 4; h++) w4[h] = mw[lane * 8 + h];

        // contrib[f2] = wbar[lane,h]*h[lane,f2]; reduce over 64 lanes
        float red[32];
        #pragma unroll
        for (int h = 0; h < 4; h++)
            #pragma unroll
            for (int o = 0; o < 8; o++) red[h * 8 + o] = acc[h * 8 + o] * w4[h];

        // 6-step reduce-scatter: after the 5 splitting steps lane holds the
        // partial for f2 = (lane>>1)&31; final xor-1 completes the sum.
        {
            bool hi = (lane & 32) != 0;
            float nr[16];
            #pragma unroll
            for (int j = 0; j < 16; j++) {
                float send = hi ? red[j] : red[j + 16];
                float keep = hi ? red[j + 16] : red[j];
                nr[j] = keep + __shfl_xor(send, 32);
            }
            #pragma unroll
            for (int j = 0; j < 16; j++) red[j] = nr[j];
        }
        {
            bool hi = (lane & 16) != 0;
            float nr[8];
            #pragma unroll
            for (int j = 0; j < 8; j++) {
                float send = hi ? red[j] : red[j + 8];
                float keep = hi ? red[j + 8] : red[j];
                nr[j] = keep + __shfl_xor(send, 16);
            }
            #pragma unroll
            for (int j = 0; j < 8; j++) red[j] = nr[j];
        }
        {
            bool hi = (lane & 8) != 0;
            float nr[4];
            #pragma unroll
            for (int j = 0; j < 4; j++) {
                float send = hi ? red[j] : red[j + 4];
                float keep = hi ? red[j + 4] : red[j];
                nr[j] = keep + __shfl_xor(send, 8);
            }
            #pragma unroll
            for (int j = 0; j < 4; j++) red[j] = nr[j];
        }
        {
            bool hi = (lane & 4) != 0;
            float nr[2];
            #pragma unroll
            for (int j = 0; j < 2; j++) {
                float send = hi ? red[j] : red[j + 2];
                float keep = hi ? red[j + 2] : red[j];
                nr[j] = keep + __shfl_xor(send, 4);
            }
            red[0] = nr[0]; red[1] = nr[1];
        }
        {
            bool hi = (lane & 2) != 0;
            float send = hi ? red[0] : red[1];
            float keep = hi ? red[1] : red[0];
            red[0] = keep + __shfl_xor(send, 2);
        }
        red[0] += __shfl_xor(red[0], 1);
        if ((lane & 1) == 0)
            gout[(b * Tc + t) * 32 + ((lane >> 1) & 31)] = red[0] * (1.f / 64.f);
    }
}

// ---------------------------------------------------------------------------
// bn2 + elu + avgpool(8):  g[B,T,32] -> p[B,192,32]
// ---------------------------------------------------------------------------
__global__ void pool2a_kernel(const float* __restrict__ a2, const float* __restrict__ c2,
                              const float* __restrict__ gp, float* __restrict__ pp)
{
    int gid = blockIdx.x * TPB + threadIdx.x;    // [0, 16*192*32)
    int f2 = gid & 31;
    int rem = gid >> 5;                          // b*192 + to
    const float a = a2[f2], c = c2[f2];
    int base = rem * 8;                          // = b*1536 + to*8
    float s = 0.f;
    #pragma unroll
    for (int j = 0; j < 8; j++) {
        float gv = gp[(base + j) * 32 + f2];
        float y = fmaf(a, gv, c);
        s += y > 0.f ? y : __expf(y) - 1.f;
    }
    pp[gid] = s * 0.125f;
}

// ---------------------------------------------------------------------------
// conv3(K=16,'same') + bn3 + elu + avgpool(4): p[B,192,32] -> out[B,32,48]
// ---------------------------------------------------------------------------
__global__ __launch_bounds__(TPB) void conv3_kernel(const float* __restrict__ pp,
                                                    const float* __restrict__ w3t,
                                                    const float* __restrict__ a3p,
                                                    const float* __restrict__ c3p,
                                                    float* __restrict__ outp)
{
    __shared__ float pl[63 * 32];
    __shared__ float q[48 * 32];
    const int tid = threadIdx.x;
    const int b = blockIdx.x >> 2, cc = blockIdx.x & 3;

    for (int idx = tid; idx < 63 * 32; idx += TPB) {
        int r = idx >> 5, f2 = idx & 31;
        int tog = cc * 48 - 7 + r;
        pl[idx] = (tog >= 0 && tog < T2c) ? pp[(b * T2c + tog) * 32 + f2] : 0.f;
    }
    __syncthreads();

    const int f2o = tid & 31, grp = tid >> 5;
    const int tb = grp * 6;
    float acc[6] = { 0.f, 0.f, 0.f, 0.f, 0.f, 0.f };
    for (int f2i = 0; f2i < 32; f2i++) {
        float seg[21];
        #pragma unroll
        for (int r = 0; r < 21; r++) seg[r] = pl[(tb + r) * 32 + f2i];
        #pragma unroll
        for (int k = 0; k < 16; k++) {
            float wv = w3t[(k * 32 + f2i) * 32 + f2o];
            #pragma unroll
            for (int j = 0; j < 6; j++)
                acc[j] = fmaf(seg[j + k], wv, acc[j]);
        }
    }
    const float a3 = a3p[f2o], c3 = c3p[f2o];
    #pragma unroll
    for (int j = 0; j < 6; j++) {
        float y = fmaf(a3, acc[j], c3);
        y = y > 0.f ? y : __expf(y) - 1.f;
        q[(tb + j) * 32 + f2o] = y;
    }
    __syncthreads();
    for (int idx = tid; idx < 12 * 32; idx += TPB) {
        int t4 = idx >> 5, f2 = idx & 31;
        int r0 = t4 * 4;
        float s = q[r0 * 32 + f2] + q[(r0 + 1) * 32 + f2] +
                  q[(r0 + 2) * 32 + f2] + q[(r0 + 3) * 32 + f2];
        outp[(b * 32 + f2) * 48 + cc * 12 + t4] = s * 0.25f;
    }
}

// ---------------------------------------------------------------------------
extern "C" void kernel_launch(void* const* d_in, const int* in_sizes, int n_in,
                              void* d_out, int out_size, void* d_ws, size_t ws_size,
                              hipStream_t stream)
{
    const float* x    = (const float*)d_in[0];
    const float* c1w  = (const float*)d_in[1];
    const float* g1   = (const float*)d_in[2];
    const float* b1   = (const float*)d_in[3];
    const float* m1   = (const float*)d_in[4];
    const float* v1   = (const float*)d_in[5];
    const float* W    = (const float*)d_in[6];
    const float* asrc = (const float*)d_in[7];
    const float* adst = (const float*)d_in[8];
    const float* bias = (const float*)d_in[9];
    const float* g2   = (const float*)d_in[10];
    const float* b2   = (const float*)d_in[11];
    const float* m2   = (const float*)d_in[12];
    const float* v2   = (const float*)d_in[13];
    const float* w3   = (const float*)d_in[14];
    const float* g3   = (const float*)d_in[15];
    const float* b3   = (const float*)d_in[16];
    const float* m3   = (const float*)d_in[17];
    const float* v3   = (const float*)d_in[18];
    const int*   ei   = (const int*)d_in[19];
    const int    ne   = in_sizes[19] / 2;

    float* ws = (float*)d_ws;

    prep_kernel<<<1, TPB, 0, stream>>>(c1w, g1, b1, m1, v1, W, bias,
                                       g2, b2, m2, v2, w3, g3, b3, m3, v3, ei, ne, ws);

    gat_kernel<<<Bc * 96, TPB, 0, stream>>>(x, asrc, adst,
                                            ws + OW_WEFF, ws + OW_CHL,
                                            (const int*)(ws + OW_CSRO),
                                            (const int*)(ws + OW_CSRS),
                                            ws + OW_G);

    pool2a_kernel<<<(Bc * T2c * F2c) / TPB, TPB, 0, stream>>>(ws + OW_A2, ws + OW_C2,
                                                              ws + OW_G, ws + OW_P);

    conv3_kernel<<<Bc * 4, TPB, 0, stream>>>(ws + OW_P, ws + OW_W3T,
                                             ws + OW_A3, ws + OW_C3, (float*)d_out);
}

// Round 3
// 405.300 us; speedup vs baseline: 1.2529x; 1.2405x over previous
//
#include <hip/hip_runtime.h>
#include <math.h>

#define TPB 256

// Problem constants
constexpr int Bc = 16, Tc = 1536;
constexpr int F2c = 32;            // H*FO = 4*8
constexpr int T2c = 192;           // T / P1
constexpr float EPSc = 1e-5f;
constexpr float NSLOPE = 0.2f;

// Workspace layout (float offsets)
constexpr int OW_WEFF = 0;                 // [32 k][32 f2]
constexpr int OW_CHL  = 1024;              // [32]
constexpr int OW_A2   = 1056;              // [32]
constexpr int OW_C2   = 1088;              // [32] (gat bias folded in)
constexpr int OW_A3   = 1120;              // [32]
constexpr int OW_C3   = 1152;              // [32]
constexpr int OW_W3T  = 1184;              // [16 k][32 f2i][32 f2o]
constexpr int OW_CSRO = OW_W3T + 16384;    // 65 ints
constexpr int OW_CSRS = OW_CSRO + 65;      // 320 ints
constexpr int OW_P    = 17984;             // [B][192][32] = 98304 floats

// ---------------------------------------------------------------------------
// Prep: fold bn1+gatW+conv1 -> weff/const; fold bn affines; transpose conv3_w;
// build CSR (incoming edges per dst) from edge_index (parallel LDS atomics).
// ---------------------------------------------------------------------------
__global__ void prep_kernel(const float* __restrict__ c1w,
                            const float* __restrict__ g1, const float* __restrict__ b1,
                            const float* __restrict__ m1, const float* __restrict__ v1,
                            const float* __restrict__ W,  const float* __restrict__ bias,
                            const float* __restrict__ g2, const float* __restrict__ b2,
                            const float* __restrict__ m2, const float* __restrict__ v2,
                            const float* __restrict__ w3,
                            const float* __restrict__ g3, const float* __restrict__ b3,
                            const float* __restrict__ m3, const float* __restrict__ v3,
                            const int* __restrict__ ei, int ne, float* __restrict__ ws)
{
    __shared__ int cnt[64];
    const int tid = threadIdx.x;

    // weff[k*32+f2] = sum_f a1[f]*W[f,f2]*w1[f,k]
    for (int idx = tid; idx < 1024; idx += TPB) {
        int k = idx >> 5, f2 = idx & 31;
        float s = 0.f;
        for (int f = 0; f < 16; f++) {
            float a1 = g1[f] * rsqrtf(v1[f] + EPSc);
            s += a1 * W[f * 32 + f2] * c1w[f * 32 + k];
        }
        ws[OW_WEFF + idx] = s;
    }
    for (int f2 = tid; f2 < 32; f2 += TPB) {
        float s = 0.f;
        for (int f = 0; f < 16; f++) {
            float a1 = g1[f] * rsqrtf(v1[f] + EPSc);
            float c1 = b1[f] - a1 * m1[f];
            s += c1 * W[f * 32 + f2];
        }
        ws[OW_CHL + f2] = s;
        float a2 = g2[f2] * rsqrtf(v2[f2] + EPSc);
        ws[OW_A2 + f2] = a2;
        ws[OW_C2 + f2] = b2[f2] + a2 * (bias[f2] - m2[f2]);   // gat bias folded
        float a3 = g3[f2] * rsqrtf(v3[f2] + EPSc);
        ws[OW_A3 + f2] = a3;
        ws[OW_C3 + f2] = b3[f2] - a3 * m3[f2];
    }
    // w3t[(k*32+f2i)*32+f2o] = w3[f2o][f2i][k]
    for (int idx = tid; idx < 16384; idx += TPB) {
        int f2o = idx & 31, r = idx >> 5;
        int f2i = r & 31, k = r >> 5;
        ws[OW_W3T + idx] = w3[(f2o * 32 + f2i) * 16 + k];
    }

    // CSR build: histogram -> prefix -> scatter
    int* co = (int*)(ws + OW_CSRO);
    int* cs = (int*)(ws + OW_CSRS);
    if (tid < 64) cnt[tid] = 0;
    __syncthreads();
    for (int e = tid; e < ne; e += TPB) atomicAdd(&cnt[ei[ne + e]], 1);
    __syncthreads();
    if (tid == 0) {
        int run = 0;
        for (int d = 0; d < 64; d++) { int c = cnt[d]; co[d] = run; cnt[d] = run; run += c; }
        co[64] = run;
    }
    __syncthreads();
    for (int e = tid; e < ne; e += TPB) {
        int d = ei[ne + e];
        int pos = atomicAdd(&cnt[d], 1);
        cs[pos] = ei[e];
    }
}

// ---------------------------------------------------------------------------
// Fused conv1+bn1+GATlinear + attention + mean(v) + bn2+elu+pool8.
// Block = (b, 8-t tile). lane = (f2, v-half); conv weights live in VGPRs.
// h[v][t][f2] stays in registers (acc[8][8] per lane, 16 v per wave).
// ---------------------------------------------------------------------------
__global__ __launch_bounds__(TPB, 3) void gat_kernel(const float* __restrict__ x,
                                                     const float* __restrict__ asrc,
                                                     const float* __restrict__ adst,
                                                     const float* __restrict__ wf,
                                                     const float* __restrict__ chl,
                                                     const float* __restrict__ a2p,
                                                     const float* __restrict__ c2p,
                                                     const int* __restrict__ co,
                                                     const int* __restrict__ cs,
                                                     float* __restrict__ pout)
{
    __shared__ __align__(16) float xt[64 * 40];     // x window [v][j], j in [t0-15, t0+24)
    __shared__ __align__(16) float es_s[8 * 256];   // [t][v*4+h]
    __shared__ __align__(16) float ed_s[8 * 256];   // [t][v*4+h]
    __shared__ __align__(16) float wb_s[8 * 256];   // [t][v*4+h] accumulated alpha-sums
    __shared__ float g_s[8 * 32];                   // [t][f2] block-level partial
    __shared__ int soff[65];
    __shared__ int ssrc[320];

    const int tid  = threadIdx.x;
    const int b    = blockIdx.x / 192;
    const int tile = blockIdx.x % 192;
    const int t0   = tile * 8;

    // Stage x window (39 cols used, stride 40 keeps 16B alignment)
    for (int idx = tid; idx < 64 * 40; idx += TPB) {
        int v = idx / 40, j = idx % 40;
        int t = t0 - 15 + j;
        xt[idx] = (j < 39 && t >= 0 && t < Tc) ? x[(b * 64 + v) * Tc + t] : 0.f;
    }
    for (int idx = tid; idx < 2048; idx += TPB) wb_s[idx] = 0.f;
    g_s[tid & 255] = 0.f;
    if (tid < 65) soff[tid] = co[tid];
    for (int idx = tid; idx < 320; idx += TPB) ssrc[idx] = cs[idx];

    const int wid = tid >> 6, lane = tid & 63;
    const int f2 = lane & 31, vh = lane >> 5, h4 = f2 >> 3;

    // one-time register loads
    float wreg[32];
    #pragma unroll
    for (int k = 0; k < 32; k++) wreg[k] = wf[k * 32 + f2];
    const float asl = asrc[f2], adl = adst[f2], chl_l = chl[f2];

    __syncthreads();

    // ---- Phase 1: conv (weights in regs) + es/ed via 8-lane shfl reduce ----
    float acc[8][8];
    #pragma unroll
    for (int i = 0; i < 8; i++) {
        const int v = wid * 16 + i * 2 + vh;
        const float* xr = &xt[v * 40];
        float a[8];
        #pragma unroll
        for (int t = 0; t < 8; t++) a[t] = chl_l;
        #pragma unroll
        for (int jb = 0; jb < 10; jb++) {
            const float4 xv = *(const float4*)(xr + jb * 4);
            const float xq[4] = { xv.x, xv.y, xv.z, xv.w };
            #pragma unroll
            for (int q = 0; q < 4; q++) {
                const int j = jb * 4 + q;
                if (j <= 38) {
                    #pragma unroll
                    for (int t = 0; t < 8; t++) {
                        const int k = j - t;
                        if (k >= 0 && k < 32)
                            a[t] = fmaf(xq[q], wreg[k], a[t]);
                    }
                }
            }
        }
        // es/ed: reduce a[t]*asrc over the 8 lanes of this head group
        float esv[8], edv[8];
        #pragma unroll
        for (int t = 0; t < 8; t++) { esv[t] = a[t] * asl; edv[t] = a[t] * adl; }
        #pragma unroll
        for (int m = 1; m <= 4; m <<= 1) {
            #pragma unroll
            for (int t = 0; t < 8; t++) {
                esv[t] += __shfl_xor(esv[t], m);
                edv[t] += __shfl_xor(edv[t], m);
            }
        }
        if ((f2 & 7) == 0) {
            const int base = v * 4 + h4;
            #pragma unroll
            for (int t = 0; t < 8; t++) {
                es_s[t * 256 + base] = esv[t];
                ed_s[t * 256 + base] = edv[t];
            }
        }
        #pragma unroll
        for (int t = 0; t < 8; t++) acc[i][t] = a[t];
    }
    __syncthreads();

    // ---- Phase 2: per-dst softmax, scatter alpha sums into wbar ----
    // (no max-subtraction: logits are O(1), fp32 exp is safe; ratio identical)
    {
        const int beg = soff[lane], end = soff[lane + 1];   // lane = dst node
        #pragma unroll
        for (int tt = 0; tt < 2; tt++) {
            const int t = wid * 2 + tt;
            const float4 e4 = *(const float4*)&ed_s[t * 256 + lane * 4];
            const float edh[4] = { e4.x, e4.y, e4.z, e4.w };
            float den[4] = { 0.f, 0.f, 0.f, 0.f };
            for (int e = beg; e < end; e++) {
                const int sn = ssrc[e];
                const float4 s4 = *(const float4*)&es_s[t * 256 + sn * 4];
                const float sh[4] = { s4.x, s4.y, s4.z, s4.w };
                #pragma unroll
                for (int h = 0; h < 4; h++) {
                    float ev = sh[h] + edh[h];
                    ev = ev > 0.f ? ev : NSLOPE * ev;
                    den[h] += __expf(ev);
                }
            }
            float rden[4];
            #pragma unroll
            for (int h = 0; h < 4; h++) rden[h] = 1.f / den[h];
            for (int e = beg; e < end; e++) {
                const int sn = ssrc[e];
                const float4 s4 = *(const float4*)&es_s[t * 256 + sn * 4];
                const float sh[4] = { s4.x, s4.y, s4.z, s4.w };
                #pragma unroll
                for (int h = 0; h < 4; h++) {
                    float ev = sh[h] + edh[h];
                    ev = ev > 0.f ? ev : NSLOPE * ev;
                    atomicAdd(&wb_s[t * 256 + sn * 4 + h], __expf(ev) * rden[h]);
                }
            }
        }
    }
    __syncthreads();

    // ---- Phase 3: g[t,f2] = sum_v wbar[t,v,h]*h[v,t,f2] using register h ----
    float gp[8] = { 0.f, 0.f, 0.f, 0.f, 0.f, 0.f, 0.f, 0.f };
    #pragma unroll
    for (int i = 0; i < 8; i++) {
        const int v = wid * 16 + i * 2 + vh;
        #pragma unroll
        for (int t = 0; t < 8; t++) {
            const float wb = wb_s[t * 256 + v * 4 + h4];
            gp[t] = fmaf(wb, acc[i][t], gp[t]);
        }
    }
    #pragma unroll
    for (int t = 0; t < 8; t++) gp[t] += __shfl_xor(gp[t], 32);
    if (lane < 32) {
        #pragma unroll
        for (int t = 0; t < 8; t++) atomicAdd(&g_s[t * 32 + f2], gp[t]);
    }
    __syncthreads();

    // ---- Epilogue: bn2 + elu + pool8 (this block is exactly one pool group) ----
    if (tid < 32) {
        const float a2l = a2p[tid], c2l = c2p[tid];
        float s = 0.f;
        #pragma unroll
        for (int t = 0; t < 8; t++) {
            float gv = g_s[t * 32 + tid] * (1.f / 64.f);
            float y = fmaf(a2l, gv, c2l);
            s += y > 0.f ? y : __expf(y) - 1.f;
        }
        pout[(b * T2c + tile) * 32 + tid] = s * 0.125f;
    }
}

// ---------------------------------------------------------------------------
// conv3(K=16,'same') + bn3 + elu + avgpool(4): p[B,192,32] -> out[B,32,48]
// ---------------------------------------------------------------------------
__global__ __launch_bounds__(TPB) void conv3_kernel(const float* __restrict__ pp,
                                                    const float* __restrict__ w3t,
                                                    const float* __restrict__ a3p,
                                                    const float* __restrict__ c3p,
                                                    float* __restrict__ outp)
{
    __shared__ float pl[63 * 32];
    __shared__ float q[48 * 32];
    const int tid = threadIdx.x;
    const int b = blockIdx.x >> 2, cc = blockIdx.x & 3;

    for (int idx = tid; idx < 63 * 32; idx += TPB) {
        int r = idx >> 5, f2 = idx & 31;
        int tog = cc * 48 - 7 + r;
        pl[idx] = (tog >= 0 && tog < T2c) ? pp[(b * T2c + tog) * 32 + f2] : 0.f;
    }
    __syncthreads();

    const int f2o = tid & 31, grp = tid >> 5;
    const int tb = grp * 6;
    float acc[6] = { 0.f, 0.f, 0.f, 0.f, 0.f, 0.f };
    for (int f2i = 0; f2i < 32; f2i++) {
        float seg[21];
        #pragma unroll
        for (int r = 0; r < 21; r++) seg[r] = pl[(tb + r) * 32 + f2i];
        #pragma unroll
        for (int k = 0; k < 16; k++) {
            float wv = w3t[(k * 32 + f2i) * 32 + f2o];
            #pragma unroll
            for (int j = 0; j < 6; j++)
                acc[j] = fmaf(seg[j + k], wv, acc[j]);
        }
    }
    const float a3 = a3p[f2o], c3 = c3p[f2o];
    #pragma unroll
    for (int j = 0; j < 6; j++) {
        float y = fmaf(a3, acc[j], c3);
        y = y > 0.f ? y : __expf(y) - 1.f;
        q[(tb + j) * 32 + f2o] = y;
    }
    __syncthreads();
    for (int idx = tid; idx < 12 * 32; idx += TPB) {
        int t4 = idx >> 5, f2 = idx & 31;
        int r0 = t4 * 4;
        float s = q[r0 * 32 + f2] + q[(r0 + 1) * 32 + f2] +
                  q[(r0 + 2) * 32 + f2] + q[(r0 + 3) * 32 + f2];
        outp[(b * 32 + f2) * 48 + cc * 12 + t4] = s * 0.25f;
    }
}

// ---------------------------------------------------------------------------
extern "C" void kernel_launch(void* const* d_in, const int* in_sizes, int n_in,
                              void* d_out, int out_size, void* d_ws, size_t ws_size,
                              hipStream_t stream)
{
    const float* x    = (const float*)d_in[0];
    const float* c1w  = (const float*)d_in[1];
    const float* g1   = (const float*)d_in[2];
    const float* b1   = (const float*)d_in[3];
    const float* m1   = (const float*)d_in[4];
    const float* v1   = (const float*)d_in[5];
    const float* W    = (const float*)d_in[6];
    const float* asrc = (const float*)d_in[7];
    const float* adst = (const float*)d_in[8];
    const float* bias = (const float*)d_in[9];
    const float* g2   = (const float*)d_in[10];
    const float* b2   = (const float*)d_in[11];
    const float* m2   = (const float*)d_in[12];
    const float* v2   = (const float*)d_in[13];
    const float* w3   = (const float*)d_in[14];
    const float* g3   = (const float*)d_in[15];
    const float* b3   = (const float*)d_in[16];
    const float* m3   = (const float*)d_in[17];
    const float* v3   = (const float*)d_in[18];
    const int*   ei   = (const int*)d_in[19];
    const int    ne   = in_sizes[19] / 2;

    float* ws = (float*)d_ws;

    prep_kernel<<<1, TPB, 0, stream>>>(c1w, g1, b1, m1, v1, W, bias,
                                       g2, b2, m2, v2, w3, g3, b3, m3, v3, ei, ne, ws);

    gat_kernel<<<Bc * T2c, TPB, 0, stream>>>(x, asrc, adst,
                                             ws + OW_WEFF, ws + OW_CHL,
                                             ws + OW_A2, ws + OW_C2,
                                             (const int*)(ws + OW_CSRO),
                                             (const int*)(ws + OW_CSRS),
                                             ws + OW_P);

    conv3_kernel<<<Bc * 4, TPB, 0, stream>>>(ws + OW_P, ws + OW_W3T,
                                             ws + OW_A3, ws + OW_C3, (float*)d_out);
}

// Round 4
// 350.018 us; speedup vs baseline: 1.4508x; 1.1579x over previous
//
#include <hip/hip_runtime.h>
#include <math.h>

#define TPB 256

// Problem constants
constexpr int Bc = 16, Tc = 1536;
constexpr int T2c = 192;           // T / P1
constexpr float EPSc = 1e-5f;
constexpr float NSLOPE = 0.2f;

// Workspace layout (float offsets)
constexpr int OW_WEFF = 0;                 // [32 k][32 f2]
constexpr int OW_CHL  = 1024;              // [32]
constexpr int OW_A2   = 1056;              // [32]
constexpr int OW_C2   = 1088;              // [32] (gat bias folded in)
constexpr int OW_A3   = 1120;              // [32]
constexpr int OW_C3   = 1152;              // [32]
constexpr int OW_WES  = 1184;              // [32 k][4 h]  es conv weights
constexpr int OW_WED  = 1312;              // [32 k][4 h]  ed conv weights (contiguous after WES)
constexpr int OW_CES  = 1440;              // [4] + [4] ced contiguous
constexpr int OW_W3T  = 1448;              // [16 k][32 f2i][32 f2o]
constexpr int OW_CSRO = OW_W3T + 16384;    // 65 ints
constexpr int OW_CSRS = OW_CSRO + 65;      // 320 ints
constexpr int OW_P    = 18240;             // [B][192][32] = 98304 floats

// gat LDS layout (float offsets into one array)
constexpr int L_XT   = 0;                  // [64 v][41] cols 0..38 = x, col 39 = 1.0
constexpr int L_ES   = 2624;               // [8 t][v*4+h]
constexpr int L_ED   = 4672;               // [8 t][v*4+h]
constexpr int L_WB   = 6720;               // [8 t][v*4+h]
constexpr int L_Y    = 8768;               // [8 t][4 h][40 c]
constexpr int L_WE   = 10048;              // wes 128 | wed 128
constexpr int L_G    = 10304;              // [8 t][32 f2]
constexpr int L_IOFF = 10560;              // 65 ints
constexpr int L_ISRC = 10625;              // 320 ints
constexpr int L_TOT  = 10945;
constexpr int L_WBT  = L_ES;               // alias: [8 t][4 h][64 v] (ES dead after phase B)
constexpr int L_WF   = L_ED;               // alias: weff [32k][32f2] (ED dead after phase B)

// ---------------------------------------------------------------------------
// Prep: fold bn1+gatW+conv1 -> weff/const; derive es/ed conv weights; fold bn
// affines; transpose conv3_w; build CSR from edge_index.
// ---------------------------------------------------------------------------
__global__ void prep_kernel(const float* __restrict__ c1w,
                            const float* __restrict__ g1, const float* __restrict__ b1,
                            const float* __restrict__ m1, const float* __restrict__ v1,
                            const float* __restrict__ W,  const float* __restrict__ bias,
                            const float* __restrict__ asrc, const float* __restrict__ adst,
                            const float* __restrict__ g2, const float* __restrict__ b2,
                            const float* __restrict__ m2, const float* __restrict__ v2,
                            const float* __restrict__ w3,
                            const float* __restrict__ g3, const float* __restrict__ b3,
                            const float* __restrict__ m3, const float* __restrict__ v3,
                            const int* __restrict__ ei, int ne, float* __restrict__ ws)
{
    __shared__ int cnt[64];
    const int tid = threadIdx.x;

    // weff[k*32+f2] = sum_f a1[f]*W[f,f2]*w1[f,k]
    for (int idx = tid; idx < 1024; idx += TPB) {
        int k = idx >> 5, f2 = idx & 31;
        float s = 0.f;
        for (int f = 0; f < 16; f++) {
            float a1 = g1[f] * rsqrtf(v1[f] + EPSc);
            s += a1 * W[f * 32 + f2] * c1w[f * 32 + k];
        }
        ws[OW_WEFF + idx] = s;
    }
    for (int f2 = tid; f2 < 32; f2 += TPB) {
        float s = 0.f;
        for (int f = 0; f < 16; f++) {
            float a1 = g1[f] * rsqrtf(v1[f] + EPSc);
            float c1 = b1[f] - a1 * m1[f];
            s += c1 * W[f * 32 + f2];
        }
        ws[OW_CHL + f2] = s;
        float a2 = g2[f2] * rsqrtf(v2[f2] + EPSc);
        ws[OW_A2 + f2] = a2;
        ws[OW_C2 + f2] = b2[f2] + a2 * (bias[f2] - m2[f2]);   // gat bias folded
        float a3 = g3[f2] * rsqrtf(v3[f2] + EPSc);
        ws[OW_A3 + f2] = a3;
        ws[OW_C3 + f2] = b3[f2] - a3 * m3[f2];
    }
    // w3t[(k*32+f2i)*32+f2o] = w3[f2o][f2i][k]
    for (int idx = tid; idx < 16384; idx += TPB) {
        int f2o = idx & 31, r = idx >> 5;
        int f2i = r & 31, k = r >> 5;
        ws[OW_W3T + idx] = w3[(f2o * 32 + f2i) * 16 + k];
    }

    // CSR build
    int* co = (int*)(ws + OW_CSRO);
    int* cs = (int*)(ws + OW_CSRS);
    if (tid < 64) cnt[tid] = 0;
    __syncthreads();
    for (int e = tid; e < ne; e += TPB) atomicAdd(&cnt[ei[ne + e]], 1);
    __syncthreads();
    if (tid == 0) {
        int run = 0;
        for (int d = 0; d < 64; d++) { int c = cnt[d]; co[d] = run; cnt[d] = run; run += c; }
        co[64] = run;
    }
    __syncthreads();
    for (int e = tid; e < ne; e += TPB) {
        int d = ei[ne + e];
        int pos = atomicAdd(&cnt[d], 1);
        cs[pos] = ei[e];
    }

    // derive es/ed conv weights from weff (written above by this block)
    __syncthreads();
    if (tid < 128) {
        int k = tid >> 2, h = tid & 3;
        float s1 = 0.f, s2 = 0.f;
        for (int o = 0; o < 8; o++) {
            float wv = ws[OW_WEFF + k * 32 + h * 8 + o];
            s1 = fmaf(asrc[h * 8 + o], wv, s1);
            s2 = fmaf(adst[h * 8 + o], wv, s2);
        }
        ws[OW_WES + tid] = s1;
        ws[OW_WED + tid] = s2;
    }
    if (tid < 4) {
        float s1 = 0.f, s2 = 0.f;
        for (int o = 0; o < 8; o++) {
            float cv = ws[OW_CHL + tid * 8 + o];
            s1 = fmaf(asrc[tid * 8 + o], cv, s1);
            s2 = fmaf(adst[tid * 8 + o], cv, s2);
        }
        ws[OW_CES + tid] = s1;
        ws[OW_CES + 4 + tid] = s2;
    }
}

// ---------------------------------------------------------------------------
// Fused conv1+bn1+GAT + mean(v) + bn2+elu+pool8, fully factorized:
//   A: es/ed as direct 32-tap convs (thread = (v,h), reg-ring, no h matrix)
//   B: per-dst softmax -> alpha-sums wbar (lane = dst)
//   C: y[t,h,c] = sum_v wbar[t,v,h] * x[v,c]   (tiny matmul, float4 wbar)
//   D: g[t,f2]  = sum_k weff[k,f2]*y[t,h,t+k] + chl[f2]*S[t,h]
// No per-thread arrays bigger than 8 -> no AGPR spill (R3's failure mode).
// ---------------------------------------------------------------------------
__global__ __launch_bounds__(TPB, 4) void gat_kernel(const float* __restrict__ x,
                                                     const float* __restrict__ wfp,
                                                     const float* __restrict__ chlp,
                                                     const float* __restrict__ wesed,
                                                     const float* __restrict__ cesed,
                                                     const float* __restrict__ a2p,
                                                     const float* __restrict__ c2p,
                                                     const int* __restrict__ co,
                                                     const int* __restrict__ cs,
                                                     float* __restrict__ pout)
{
    __shared__ __align__(16) float sm[L_TOT];
    int* ioff = (int*)&sm[L_IOFF];
    int* isrc = (int*)&sm[L_ISRC];

    const int tid  = threadIdx.x;
    const int b    = blockIdx.x / 192;
    const int tile = blockIdx.x % 192;
    const int t0   = tile * 8;

    // ---- stage: x window (cols 0..38; col 39 = 1.0 for the S-column), CSR,
    //      wes/wed, zero wbar ----
    for (int idx = tid; idx < 64 * 41; idx += TPB) {
        int v = idx / 41, j = idx % 41;
        float val = 1.0f;
        if (j < 39) {
            int t = t0 - 15 + j;
            val = (t >= 0 && t < Tc) ? x[(b * 64 + v) * Tc + t] : 0.f;
        }
        sm[L_XT + idx] = val;
    }
    sm[L_WE + tid] = wesed[tid];            // 256 = wes(128)+wed(128)
    for (int idx = tid; idx < 2048; idx += TPB) sm[L_WB + idx] = 0.f;
    if (tid < 65) ioff[tid] = co[tid];
    for (int idx = tid; idx < 320; idx += TPB) isrc[idx] = cs[idx];
    __syncthreads();

    // ---- Phase A: es/ed convs, thread = (v,h) ----
    {
        const int v = tid >> 2, h = tid & 3;
        const float cesh = cesed[h], cedh = cesed[4 + h];
        const float* xrow = &sm[L_XT + v * 41];
        float aes[8], aed[8];
        #pragma unroll
        for (int t = 0; t < 8; t++) { aes[t] = cesh; aed[t] = cedh; }
        float xr[8];
        #pragma unroll
        for (int q = 0; q < 7; q++) xr[q] = xrow[q];
        #pragma unroll
        for (int k = 0; k < 32; k++) {
            xr[(k + 7) & 7] = xrow[k + 7];
            const float wek = sm[L_WE + k * 4 + h];
            const float wdk = sm[L_WE + 128 + k * 4 + h];
            #pragma unroll
            for (int t = 0; t < 8; t++) {
                const float xv = xr[(k + t) & 7];
                aes[t] = fmaf(xv, wek, aes[t]);
                aed[t] = fmaf(xv, wdk, aed[t]);
            }
        }
        #pragma unroll
        for (int t = 0; t < 8; t++) {
            sm[L_ES + t * 256 + v * 4 + h] = aes[t];
            sm[L_ED + t * 256 + v * 4 + h] = aed[t];
        }
    }
    __syncthreads();

    // ---- Phase B: per-dst softmax, scatter alpha-sums into wbar ----
    // (no max-subtraction: logits O(1), fp32 exp safe; ratio identical)
    {
        const int wid = tid >> 6, lane = tid & 63;
        const int beg = ioff[lane], end = ioff[lane + 1];
        #pragma unroll
        for (int tt = 0; tt < 2; tt++) {
            const int t = wid * 2 + tt;
            const float4 e4 = *(const float4*)&sm[L_ED + t * 256 + lane * 4];
            const float edh[4] = { e4.x, e4.y, e4.z, e4.w };
            float den[4] = { 0.f, 0.f, 0.f, 0.f };
            for (int e = beg; e < end; e++) {
                const int sn = isrc[e];
                const float4 s4 = *(const float4*)&sm[L_ES + t * 256 + sn * 4];
                const float sh[4] = { s4.x, s4.y, s4.z, s4.w };
                #pragma unroll
                for (int h = 0; h < 4; h++) {
                    float ev = sh[h] + edh[h];
                    ev = ev > 0.f ? ev : NSLOPE * ev;
                    den[h] += __expf(ev);
                }
            }
            float rden[4];
            #pragma unroll
            for (int h = 0; h < 4; h++) rden[h] = 1.f / den[h];
            for (int e = beg; e < end; e++) {
                const int sn = isrc[e];
                const float4 s4 = *(const float4*)&sm[L_ES + t * 256 + sn * 4];
                const float sh[4] = { s4.x, s4.y, s4.z, s4.w };
                #pragma unroll
                for (int h = 0; h < 4; h++) {
                    float ev = sh[h] + edh[h];
                    ev = ev > 0.f ? ev : NSLOPE * ev;
                    atomicAdd(&sm[L_WB + t * 256 + sn * 4 + h], __expf(ev) * rden[h]);
                }
            }
        }
    }
    __syncthreads();

    // ---- transpose wbar -> [t][h][v] (into dead ES) + stage weff (into dead ED) ----
    for (int idx = tid; idx < 2048; idx += TPB) {
        int t = idx >> 8, r = idx & 255, v = r >> 2, h = r & 3;
        sm[L_WBT + t * 256 + h * 64 + v] = sm[L_WB + idx];
    }
    for (int idx = tid; idx < 1024; idx += TPB) sm[L_WF + idx] = wfp[idx];
    __syncthreads();

    // ---- Phase C: y[t,h,c] = sum_v wbT[t,h,v]*x[v,c]; c=39 gives S[t,h] ----
    if (tid < 160) {
        const int h = tid / 40, c = tid % 40;
        float ya[8] = { 0.f, 0.f, 0.f, 0.f, 0.f, 0.f, 0.f, 0.f };
        #pragma unroll 4
        for (int v4 = 0; v4 < 16; v4++) {
            float xq[4];
            #pragma unroll
            for (int q = 0; q < 4; q++) xq[q] = sm[L_XT + (v4 * 4 + q) * 41 + c];
            #pragma unroll
            for (int t = 0; t < 8; t++) {
                const float4 w4 = *(const float4*)&sm[L_WBT + t * 256 + h * 64 + v4 * 4];
                ya[t] = fmaf(w4.x, xq[0], fmaf(w4.y, xq[1],
                        fmaf(w4.z, xq[2], fmaf(w4.w, xq[3], ya[t]))));
            }
        }
        #pragma unroll
        for (int t = 0; t < 8; t++) sm[L_Y + (t * 4 + h) * 40 + c] = ya[t];
    }
    __syncthreads();

    // ---- Phase D: g[t,f2] = sum_k weff[k,f2]*y[t,h,t+k] + chl[f2]*S ----
    {
        const int t = tid >> 5, f2 = tid & 31, h = f2 >> 3;
        const float* yrow = &sm[L_Y + (t * 4 + h) * 40];
        float acc = chlp[f2] * yrow[39];
        #pragma unroll
        for (int k = 0; k < 32; k++)
            acc = fmaf(sm[L_WF + k * 32 + f2], yrow[t + k], acc);
        sm[L_G + t * 32 + f2] = acc;
    }
    __syncthreads();

    // ---- Epilogue: bn2 + elu + pool8 (block = exactly one pool group) ----
    if (tid < 32) {
        const float a2l = a2p[tid], c2l = c2p[tid];
        float s = 0.f;
        #pragma unroll
        for (int t = 0; t < 8; t++) {
            float gv = sm[L_G + t * 32 + tid] * (1.f / 64.f);
            float y = fmaf(a2l, gv, c2l);
            s += y > 0.f ? y : __expf(y) - 1.f;
        }
        pout[(b * T2c + tile) * 32 + tid] = s * 0.125f;
    }
}

// ---------------------------------------------------------------------------
// conv3(K=16,'same') + bn3 + elu + avgpool(4): p[B,192,32] -> out[B,32,48]
// ---------------------------------------------------------------------------
__global__ __launch_bounds__(TPB) void conv3_kernel(const float* __restrict__ pp,
                                                    const float* __restrict__ w3t,
                                                    const float* __restrict__ a3p,
                                                    const float* __restrict__ c3p,
                                                    float* __restrict__ outp)
{
    __shared__ float pl[63 * 32];
    __shared__ float q[48 * 32];
    const int tid = threadIdx.x;
    const int b = blockIdx.x >> 2, cc = blockIdx.x & 3;

    for (int idx = tid; idx < 63 * 32; idx += TPB) {
        int r = idx >> 5, f2 = idx & 31;
        int tog = cc * 48 - 7 + r;
        pl[idx] = (tog >= 0 && tog < T2c) ? pp[(b * T2c + tog) * 32 + f2] : 0.f;
    }
    __syncthreads();

    const int f2o = tid & 31, grp = tid >> 5;
    const int tb = grp * 6;
    float acc[6] = { 0.f, 0.f, 0.f, 0.f, 0.f, 0.f };
    for (int f2i = 0; f2i < 32; f2i++) {
        float seg[21];
        #pragma unroll
        for (int r = 0; r < 21; r++) seg[r] = pl[(tb + r) * 32 + f2i];
        #pragma unroll
        for (int k = 0; k < 16; k++) {
            float wv = w3t[(k * 32 + f2i) * 32 + f2o];
            #pragma unroll
            for (int j = 0; j < 6; j++)
                acc[j] = fmaf(seg[j + k], wv, acc[j]);
        }
    }
    const float a3 = a3p[f2o], c3 = c3p[f2o];
    #pragma unroll
    for (int j = 0; j < 6; j++) {
        float y = fmaf(a3, acc[j], c3);
        y = y > 0.f ? y : __expf(y) - 1.f;
        q[(tb + j) * 32 + f2o] = y;
    }
    __syncthreads();
    for (int idx = tid; idx < 12 * 32; idx += TPB) {
        int t4 = idx >> 5, f2 = idx & 31;
        int r0 = t4 * 4;
        float s = q[r0 * 32 + f2] + q[(r0 + 1) * 32 + f2] +
                  q[(r0 + 2) * 32 + f2] + q[(r0 + 3) * 32 + f2];
        outp[(b * 32 + f2) * 48 + cc * 12 + t4] = s * 0.25f;
    }
}

// ---------------------------------------------------------------------------
extern "C" void kernel_launch(void* const* d_in, const int* in_sizes, int n_in,
                              void* d_out, int out_size, void* d_ws, size_t ws_size,
                              hipStream_t stream)
{
    const float* x    = (const float*)d_in[0];
    const float* c1w  = (const float*)d_in[1];
    const float* g1   = (const float*)d_in[2];
    const float* b1   = (const float*)d_in[3];
    const float* m1   = (const float*)d_in[4];
    const float* v1   = (const float*)d_in[5];
    const float* W    = (const float*)d_in[6];
    const float* asrc = (const float*)d_in[7];
    const float* adst = (const float*)d_in[8];
    const float* bias = (const float*)d_in[9];
    const float* g2   = (const float*)d_in[10];
    const float* b2   = (const float*)d_in[11];
    const float* m2   = (const float*)d_in[12];
    const float* v2   = (const float*)d_in[13];
    const float* w3   = (const float*)d_in[14];
    const float* g3   = (const float*)d_in[15];
    const float* b3   = (const float*)d_in[16];
    const float* m3   = (const float*)d_in[17];
    const float* v3   = (const float*)d_in[18];
    const int*   ei   = (const int*)d_in[19];
    const int    ne   = in_sizes[19] / 2;

    float* ws = (float*)d_ws;

    prep_kernel<<<1, TPB, 0, stream>>>(c1w, g1, b1, m1, v1, W, bias, asrc, adst,
                                       g2, b2, m2, v2, w3, g3, b3, m3, v3, ei, ne, ws);

    gat_kernel<<<Bc * T2c, TPB, 0, stream>>>(x,
                                             ws + OW_WEFF, ws + OW_CHL,
                                             ws + OW_WES, ws + OW_CES,
                                             ws + OW_A2, ws + OW_C2,
                                             (const int*)(ws + OW_CSRO),
                                             (const int*)(ws + OW_CSRS),
                                             ws + OW_P);

    conv3_kernel<<<Bc * 4, TPB, 0, stream>>>(ws + OW_P, ws + OW_W3T,
                                             ws + OW_A3, ws + OW_C3, (float*)d_out);
}

// Round 5
// 184.290 us; speedup vs baseline: 2.7554x; 1.8993x over previous
//
#include <hip/hip_runtime.h>
#include <math.h>

#define TPB 256

// Problem constants
constexpr int Bc = 16, Tc = 1536;
constexpr int T2c = 192;           // T / P1
constexpr float EPSc = 1e-5f;
constexpr float NSLOPE = 0.2f;
constexpr int MDI = 16;            // padded in-degree stride
constexpr int MDO = 8;             // padded out-degree stride

// Workspace layout (float offsets)
constexpr int OW_WEFF = 0;                 // [32 k][32 f2]
constexpr int OW_CHL  = 1024;              // [32]
constexpr int OW_A2   = 1056;              // [32]
constexpr int OW_C2   = 1088;              // [32] (gat bias folded in)
constexpr int OW_A3   = 1120;              // [32]
constexpr int OW_C3   = 1152;              // [32]
constexpr int OW_WES  = 1184;              // [32 k][4 h]
constexpr int OW_WED  = 1312;              // [32 k][4 h]
constexpr int OW_CES  = 1440;              // [4]+[4]
constexpr int OW_W3T  = 1448;              // [16 k][32 f2i][32 f2o]
constexpr int OW_GRAPH= OW_W3T + 16384;    // 512 floats: packed byte graph
constexpr int OW_P    = OW_GRAPH + 512;    // [B][192][32]

// Packed graph byte offsets (within OW_GRAPH region)
//   [0,1024)   isrcp[d*16+e]   in-sources, padded with 0
//   [1024,1088) indeg[d]
//   [1088,1600) outdst[v*8+j]  out-dsts, padded with 0
//   [1600,1664) outdeg[v]
//   [1664]      max in-degree   [1665] max out-degree
constexpr int GB_INTS = 417;               // 1668 bytes

// gat LDS layout (float offsets)
constexpr int L_XT  = 0;                   // [64 v][41]: c 0..38 = x window, c39 = 1.0
constexpr int L_WBT = 2624;                // [8 t][4 h][64 v]
constexpr int L_Y   = 4672;                // [8 t][4 h][40 c]
constexpr int L_WE  = 5952;                // wes 128 | wed 128
constexpr int L_G   = 6208;                // [8 t][32 f2]
constexpr int L_GR  = 6464;                // 417 ints packed graph
constexpr int L_TOT = 6884;                // 27.5 KB -> 5 blocks/CU

// ---------------------------------------------------------------------------
// Prep (grid=17): block 0 = weight folding + packed CSR/CSC; blocks 1..16 =
// conv3 weight transpose chunks. No inter-block dependencies.
// ---------------------------------------------------------------------------
__global__ void prep_kernel(const float* __restrict__ c1w,
                            const float* __restrict__ g1, const float* __restrict__ b1,
                            const float* __restrict__ m1, const float* __restrict__ v1,
                            const float* __restrict__ W,  const float* __restrict__ bias,
                            const float* __restrict__ asrc, const float* __restrict__ adst,
                            const float* __restrict__ g2, const float* __restrict__ b2,
                            const float* __restrict__ m2, const float* __restrict__ v2,
                            const float* __restrict__ w3,
                            const float* __restrict__ g3, const float* __restrict__ b3,
                            const float* __restrict__ m3, const float* __restrict__ v3,
                            const int* __restrict__ ei, int ne, float* __restrict__ ws)
{
    const int tid = threadIdx.x;
    if (blockIdx.x > 0) {
        // w3t[(k*32+f2i)*32+f2o] = w3[f2o][f2i][k]
        const int base = (blockIdx.x - 1) * 1024;
        for (int q = 0; q < 4; q++) {
            int idx = base + q * TPB + tid;
            int f2o = idx & 31, r = idx >> 5;
            int f2i = r & 31, k = r >> 5;
            ws[OW_W3T + idx] = w3[(f2o * 32 + f2i) * 16 + k];
        }
        return;
    }

    __shared__ float sweff[1024];
    __shared__ float schl[32];
    __shared__ int isrcp_i[64 * MDI];
    __shared__ int outdst_i[64 * MDO];
    __shared__ int indeg_i[64], inslot[64], outdeg_i[64], outslot[64];

    // weff[k*32+f2] = sum_f a1[f]*W[f,f2]*w1[f,k]
    for (int idx = tid; idx < 1024; idx += TPB) {
        int k = idx >> 5, f2 = idx & 31;
        float s = 0.f;
        for (int f = 0; f < 16; f++) {
            float a1 = g1[f] * rsqrtf(v1[f] + EPSc);
            s += a1 * W[f * 32 + f2] * c1w[f * 32 + k];
        }
        ws[OW_WEFF + idx] = s;
        sweff[idx] = s;
    }
    for (int f2 = tid; f2 < 32; f2 += TPB) {
        float s = 0.f;
        for (int f = 0; f < 16; f++) {
            float a1 = g1[f] * rsqrtf(v1[f] + EPSc);
            float c1 = b1[f] - a1 * m1[f];
            s += c1 * W[f * 32 + f2];
        }
        ws[OW_CHL + f2] = s;
        schl[f2] = s;
        float a2 = g2[f2] * rsqrtf(v2[f2] + EPSc);
        ws[OW_A2 + f2] = a2;
        ws[OW_C2 + f2] = b2[f2] + a2 * (bias[f2] - m2[f2]);   // gat bias folded
        float a3 = g3[f2] * rsqrtf(v3[f2] + EPSc);
        ws[OW_A3 + f2] = a3;
        ws[OW_C3 + f2] = b3[f2] - a3 * m3[f2];
    }

    // graph: padded in-lists (CSR) and out-lists (CSC) as bytes
    for (int i = tid; i < 64 * MDI; i += TPB) isrcp_i[i] = 0;
    for (int i = tid; i < 64 * MDO; i += TPB) outdst_i[i] = 0;
    if (tid < 64) { indeg_i[tid] = 0; inslot[tid] = 0; outdeg_i[tid] = 0; outslot[tid] = 0; }
    __syncthreads();
    for (int e = tid; e < ne; e += TPB) {
        atomicAdd(&indeg_i[ei[ne + e]], 1);
        atomicAdd(&outdeg_i[ei[e]], 1);
    }
    __syncthreads();
    for (int e = tid; e < ne; e += TPB) {
        int s = ei[e], d = ei[ne + e];
        int pi = atomicAdd(&inslot[d], 1);
        if (pi < MDI) isrcp_i[d * MDI + pi] = s;
        int po = atomicAdd(&outslot[s], 1);
        if (po < MDO) outdst_i[s * MDO + po] = d;
    }
    // wes/wed from LDS copy of weff
    __syncthreads();
    if (tid < 128) {
        int k = tid >> 2, h = tid & 3;
        float s1 = 0.f, s2 = 0.f;
        for (int o = 0; o < 8; o++) {
            float wv = sweff[k * 32 + h * 8 + o];
            s1 = fmaf(asrc[h * 8 + o], wv, s1);
            s2 = fmaf(adst[h * 8 + o], wv, s2);
        }
        ws[OW_WES + tid] = s1;
        ws[OW_WED + tid] = s2;
    }
    if (tid < 4) {
        float s1 = 0.f, s2 = 0.f;
        for (int o = 0; o < 8; o++) {
            float cv = schl[tid * 8 + o];
            s1 = fmaf(asrc[tid * 8 + o], cv, s1);
            s2 = fmaf(adst[tid * 8 + o], cv, s2);
        }
        ws[OW_CES + tid] = s1;
        ws[OW_CES + 4 + tid] = s2;
    }
    // pack graph to bytes
    unsigned char* gb = (unsigned char*)(ws + OW_GRAPH);
    for (int i = tid; i < 64 * MDI; i += TPB) gb[i] = (unsigned char)isrcp_i[i];
    for (int i = tid; i < 64; i += TPB) {
        gb[1024 + i] = (unsigned char)(indeg_i[i] < MDI ? indeg_i[i] : MDI);
        gb[1600 + i] = (unsigned char)(outdeg_i[i] < MDO ? outdeg_i[i] : MDO);
    }
    for (int i = tid; i < 64 * MDO; i += TPB) gb[1088 + i] = (unsigned char)outdst_i[i];
    if (tid == 0) {
        int mi = 0, mo = 0;
        for (int d = 0; d < 64; d++) {
            int a = indeg_i[d] < MDI ? indeg_i[d] : MDI;
            int b2_ = outdeg_i[d] < MDO ? outdeg_i[d] : MDO;
            mi = a > mi ? a : mi;
            mo = b2_ > mo ? b2_ : mo;
        }
        gb[1664] = (unsigned char)mi;
        gb[1665] = (unsigned char)mo;
    }
}

// ---------------------------------------------------------------------------
// Fused conv1+bn1+GAT + mean(v) + bn2+elu+pool8.
// wave = head, lane = node: es/ed/attention all in registers + shfl;
// no LDS atomics, no barriers in the conv/attention middle.
//   A: es/ed 32-tap convs (reg ring over x in LDS)
//   B: shfl softmax (pass1 dst-gather via in-lists, pass2 src-gather via
//      out-lists) -> wb[v,h,t] written once to LDS
//   C: y[t,h,c] = sum_v wb * x[v,c]  (c=39 ones-column gives S)
//   D: g[t,f2]  = sum_k weff[k,f2]*y[t,h,t+k] + chl[f2]*S[t,h]
// ---------------------------------------------------------------------------
__global__ __launch_bounds__(TPB, 5) void gat_kernel(const float* __restrict__ x,
                                                     const float* __restrict__ wfp,
                                                     const float* __restrict__ chlp,
                                                     const float* __restrict__ wesed,
                                                     const float* __restrict__ cesed,
                                                     const float* __restrict__ a2p,
                                                     const float* __restrict__ c2p,
                                                     const int* __restrict__ graphi,
                                                     float* __restrict__ pout)
{
    __shared__ __align__(16) float sm[L_TOT];

    const int tid  = threadIdx.x;
    const int b    = blockIdx.x / 192;
    const int tile = blockIdx.x % 192;
    const int t0   = tile * 8;

    // stage x window (39 cols; col 39 = 1.0; col 40 pad), weights, graph
    for (int idx = tid; idx < 64 * 41; idx += TPB) {
        int v = idx / 41, j = idx % 41;
        float val = 0.f;
        if (j < 39) {
            int t = t0 - 15 + j;
            val = (t >= 0 && t < Tc) ? x[(b * 64 + v) * Tc + t] : 0.f;
        } else if (j == 39) val = 1.0f;
        sm[L_XT + idx] = val;
    }
    sm[L_WE + tid] = wesed[tid];
    {
        int* gd = (int*)&sm[L_GR];
        for (int idx = tid; idx < GB_INTS; idx += TPB) gd[idx] = graphi[idx];
    }
    __syncthreads();

    const int wid = tid >> 6, v = tid & 63;   // wave = head, lane = node
    const unsigned char* gb = (const unsigned char*)&sm[L_GR];

    // ---- Phase A: es/ed convs (all register) ----
    float aes[8], aed[8];
    {
        const float cesh = cesed[wid], cedh = cesed[4 + wid];
        const float* xrow = &sm[L_XT + v * 41];
        #pragma unroll
        for (int t = 0; t < 8; t++) { aes[t] = cesh; aed[t] = cedh; }
        float xr[8];
        #pragma unroll
        for (int q = 0; q < 7; q++) xr[q] = xrow[q];
        #pragma unroll
        for (int k = 0; k < 32; k++) {
            xr[(k + 7) & 7] = xrow[k + 7];
            const float wek = sm[L_WE + k * 4 + wid];
            const float wdk = sm[L_WE + 128 + k * 4 + wid];
            #pragma unroll
            for (int t = 0; t < 8; t++) {
                const float xv = xr[(k + t) & 7];
                aes[t] = fmaf(xv, wek, aes[t]);
                aed[t] = fmaf(xv, wdk, aed[t]);
            }
        }
    }

    // ---- Phase B: shfl-based softmax (no max-shift: logits O(1), exact ratio) ----
    {
        const int indeg = gb[1024 + v];
        const int mdin  = gb[1664];            // wave-uniform
        float den[8] = { 0.f,0.f,0.f,0.f,0.f,0.f,0.f,0.f };
        for (int e = 0; e < mdin; e++) {
            const int s = gb[v * MDI + e];
            const float valid = (e < indeg) ? 1.f : 0.f;
            #pragma unroll
            for (int t = 0; t < 8; t++) {
                float ev = __shfl(aes[t], s) + aed[t];
                ev = ev > 0.f ? ev : NSLOPE * ev;
                den[t] += valid * __expf(ev);
            }
        }
        float rden[8];
        #pragma unroll
        for (int t = 0; t < 8; t++) rden[t] = 1.f / den[t];

        const int odeg = gb[1600 + v];
        const int mdo  = gb[1665];             // wave-uniform
        float wb[8] = { 0.f,0.f,0.f,0.f,0.f,0.f,0.f,0.f };
        for (int j = 0; j < mdo; j++) {
            const int d = gb[1088 + v * MDO + j];
            const float valid = (j < odeg) ? 1.f : 0.f;
            #pragma unroll
            for (int t = 0; t < 8; t++) {
                float ev = aes[t] + __shfl(aed[t], d);
                ev = ev > 0.f ? ev : NSLOPE * ev;
                wb[t] += valid * __expf(ev) * __shfl(rden[t], d);
            }
        }
        #pragma unroll
        for (int t = 0; t < 8; t++) sm[L_WBT + t * 256 + wid * 64 + v] = wb[t];
    }
    __syncthreads();

    // ---- Phase C: y[t,h,c] = sum_v wb[t,h,v] * x[v,c] ----
    if (tid < 160) {
        const int h = tid / 40, c = tid % 40;
        float ya[8] = { 0.f,0.f,0.f,0.f,0.f,0.f,0.f,0.f };
        #pragma unroll 4
        for (int v4 = 0; v4 < 16; v4++) {
            float xq[4];
            #pragma unroll
            for (int q = 0; q < 4; q++) xq[q] = sm[L_XT + (v4 * 4 + q) * 41 + c];
            #pragma unroll
            for (int t = 0; t < 8; t++) {
                const float4 w4 = *(const float4*)&sm[L_WBT + t * 256 + h * 64 + v4 * 4];
                ya[t] = fmaf(w4.x, xq[0], fmaf(w4.y, xq[1],
                        fmaf(w4.z, xq[2], fmaf(w4.w, xq[3], ya[t]))));
            }
        }
        #pragma unroll
        for (int t = 0; t < 8; t++) sm[L_Y + (t * 4 + h) * 40 + c] = ya[t];
    }
    __syncthreads();

    // ---- Phase D: g[t,f2] = sum_k weff[k,f2]*y[t,h,t+k] + chl[f2]*S[t,h] ----
    {
        const int t = tid >> 5, f2 = tid & 31, h = f2 >> 3;
        const float* yrow = &sm[L_Y + (t * 4 + h) * 40];
        float acc = chlp[f2] * yrow[39];
        #pragma unroll
        for (int k = 0; k < 32; k++)
            acc = fmaf(wfp[k * 32 + f2], yrow[t + k], acc);
        sm[L_G + t * 32 + f2] = acc;
    }
    __syncthreads();

    // ---- Epilogue: bn2 + elu + pool8 (block = one pool group) ----
    if (tid < 32) {
        const float a2l = a2p[tid], c2l = c2p[tid];
        float s = 0.f;
        #pragma unroll
        for (int t = 0; t < 8; t++) {
            float gv = sm[L_G + t * 32 + tid] * (1.f / 64.f);
            float y = fmaf(a2l, gv, c2l);
            s += y > 0.f ? y : __expf(y) - 1.f;
        }
        pout[(b * T2c + tile) * 32 + tid] = s * 0.125f;
    }
}

// ---------------------------------------------------------------------------
// conv3(K=16,'same') + bn3 + elu + avgpool(4): p[B,192,32] -> out[B,32,48]
// ---------------------------------------------------------------------------
__global__ __launch_bounds__(TPB) void conv3_kernel(const float* __restrict__ pp,
                                                    const float* __restrict__ w3t,
                                                    const float* __restrict__ a3p,
                                                    const float* __restrict__ c3p,
                                                    float* __restrict__ outp)
{
    __shared__ float pl[63 * 32];
    __shared__ float q[48 * 32];
    const int tid = threadIdx.x;
    const int b = blockIdx.x >> 2, cc = blockIdx.x & 3;

    for (int idx = tid; idx < 63 * 32; idx += TPB) {
        int r = idx >> 5, f2 = idx & 31;
        int tog = cc * 48 - 7 + r;
        pl[idx] = (tog >= 0 && tog < T2c) ? pp[(b * T2c + tog) * 32 + f2] : 0.f;
    }
    __syncthreads();

    const int f2o = tid & 31, grp = tid >> 5;
    const int tb = grp * 6;
    float acc[6] = { 0.f, 0.f, 0.f, 0.f, 0.f, 0.f };
    for (int f2i = 0; f2i < 32; f2i++) {
        float seg[21];
        #pragma unroll
        for (int r = 0; r < 21; r++) seg[r] = pl[(tb + r) * 32 + f2i];
        #pragma unroll
        for (int k = 0; k < 16; k++) {
            float wv = w3t[(k * 32 + f2i) * 32 + f2o];
            #pragma unroll
            for (int j = 0; j < 6; j++)
                acc[j] = fmaf(seg[j + k], wv, acc[j]);
        }
    }
    const float a3 = a3p[f2o], c3 = c3p[f2o];
    #pragma unroll
    for (int j = 0; j < 6; j++) {
        float y = fmaf(a3, acc[j], c3);
        y = y > 0.f ? y : __expf(y) - 1.f;
        q[(tb + j) * 32 + f2o] = y;
    }
    __syncthreads();
    for (int idx = tid; idx < 12 * 32; idx += TPB) {
        int t4 = idx >> 5, f2 = idx & 31;
        int r0 = t4 * 4;
        float s = q[r0 * 32 + f2] + q[(r0 + 1) * 32 + f2] +
                  q[(r0 + 2) * 32 + f2] + q[(r0 + 3) * 32 + f2];
        outp[(b * 32 + f2) * 48 + cc * 12 + t4] = s * 0.25f;
    }
}

// ---------------------------------------------------------------------------
extern "C" void kernel_launch(void* const* d_in, const int* in_sizes, int n_in,
                              void* d_out, int out_size, void* d_ws, size_t ws_size,
                              hipStream_t stream)
{
    const float* x    = (const float*)d_in[0];
    const float* c1w  = (const float*)d_in[1];
    const float* g1   = (const float*)d_in[2];
    const float* b1   = (const float*)d_in[3];
    const float* m1   = (const float*)d_in[4];
    const float* v1   = (const float*)d_in[5];
    const float* W    = (const float*)d_in[6];
    const float* asrc = (const float*)d_in[7];
    const float* adst = (const float*)d_in[8];
    const float* bias = (const float*)d_in[9];
    const float* g2   = (const float*)d_in[10];
    const float* b2   = (const float*)d_in[11];
    const float* m2   = (const float*)d_in[12];
    const float* v2   = (const float*)d_in[13];
    const float* w3   = (const float*)d_in[14];
    const float* g3   = (const float*)d_in[15];
    const float* b3   = (const float*)d_in[16];
    const float* m3   = (const float*)d_in[17];
    const float* v3   = (const float*)d_in[18];
    const int*   ei   = (const int*)d_in[19];
    const int    ne   = in_sizes[19] / 2;

    float* ws = (float*)d_ws;

    prep_kernel<<<17, TPB, 0, stream>>>(c1w, g1, b1, m1, v1, W, bias, asrc, adst,
                                        g2, b2, m2, v2, w3, g3, b3, m3, v3, ei, ne, ws);

    gat_kernel<<<Bc * T2c, TPB, 0, stream>>>(x,
                                             ws + OW_WEFF, ws + OW_CHL,
                                             ws + OW_WES, ws + OW_CES,
                                             ws + OW_A2, ws + OW_C2,
                                             (const int*)(ws + OW_GRAPH),
                                             ws + OW_P);

    conv3_kernel<<<Bc * 4, TPB, 0, stream>>>(ws + OW_P, ws + OW_W3T,
                                             ws + OW_A3, ws + OW_C3, (float*)d_out);
}

// Round 6
// 179.159 us; speedup vs baseline: 2.8343x; 1.0286x over previous
//
#include <hip/hip_runtime.h>
#include <math.h>

#define TPB 256

// Problem constants
constexpr int Bc = 16, Tc = 1536;
constexpr int T2c = 192;           // T / P1
constexpr float EPSc = 1e-5f;
constexpr float NSLOPE = 0.2f;
constexpr int MDI = 16;            // padded in-degree stride
constexpr int MDO = 8;             // padded out-degree stride

// Workspace layout (float offsets)
constexpr int OW_WEFF = 0;                 // [32 k][32 f2]
constexpr int OW_CHL  = 1024;              // [32]
constexpr int OW_A2   = 1056;              // [32]
constexpr int OW_C2   = 1088;              // [32] (gat bias folded in)
constexpr int OW_WES  = 1184;              // [32 k][4 h] | [32 k][4 h] wed (contiguous 256)
constexpr int OW_CES  = 1440;              // [4]+[4]
constexpr int OW_GRAPH= 1448;              // packed byte graph (417 ints)
constexpr int OW_P    = 1872;              // [B][192][32]

// Packed graph byte offsets:
//   [0,1024)    isrcp[d*16+e]  in-sources (pad 0)
//   [1024,1088) indeg[d]
//   [1088,1600) outdst[v*8+j]  out-dsts (pad 0)
//   [1600,1664) outdeg[v]
//   [1664] max in-degree   [1665] max out-degree
constexpr int GB_INTS = 417;

// gat LDS layout (float offsets)
constexpr int L_XT  = 0;                   // [64 v][41]: c0..38 = x window, c39 = 1.0
constexpr int L_WF  = 2624;                // weff [32k][32f2]
constexpr int L_WE  = 3648;                // wes 128 | wed 128
constexpr int L_WB  = 3904;                // [4 h][8 t][65] (stride 65: bank-spread)
constexpr int L_Y   = 5984;                // [4 h][8 t][41]
constexpr int L_G   = 7296;                // [8 t][32 f2]
constexpr int L_CHL = 7552;                // [32]
constexpr int L_GR  = 7584;                // 417 ints
constexpr int L_TOT = 8001;                // 32004 B -> 5 blocks/CU

// ---------------------------------------------------------------------------
// Prep (1 block): fold bn1+gatW+conv1 -> weff/chl; es/ed conv weights; bn2
// affine; packed graph. (conv3 weights/affine handled inside conv3_kernel.)
// ---------------------------------------------------------------------------
__global__ void prep_kernel(const float* __restrict__ c1w,
                            const float* __restrict__ g1, const float* __restrict__ b1,
                            const float* __restrict__ m1, const float* __restrict__ v1,
                            const float* __restrict__ W,  const float* __restrict__ bias,
                            const float* __restrict__ asrc, const float* __restrict__ adst,
                            const float* __restrict__ g2, const float* __restrict__ b2,
                            const float* __restrict__ m2, const float* __restrict__ v2,
                            const int* __restrict__ ei, int ne, float* __restrict__ ws)
{
    const int tid = threadIdx.x;
    __shared__ float sweff[1024];
    __shared__ float schl[32];
    __shared__ int isrcp_i[64 * MDI];
    __shared__ int outdst_i[64 * MDO];
    __shared__ int inslot[64], outslot[64];

    // weff[k*32+f2] = sum_f a1[f]*W[f,f2]*w1[f,k]
    for (int idx = tid; idx < 1024; idx += TPB) {
        int k = idx >> 5, f2 = idx & 31;
        float s = 0.f;
        for (int f = 0; f < 16; f++) {
            float a1 = g1[f] * rsqrtf(v1[f] + EPSc);
            s += a1 * W[f * 32 + f2] * c1w[f * 32 + k];
        }
        ws[OW_WEFF + idx] = s;
        sweff[idx] = s;
    }
    for (int f2 = tid; f2 < 32; f2 += TPB) {
        float s = 0.f;
        for (int f = 0; f < 16; f++) {
            float a1 = g1[f] * rsqrtf(v1[f] + EPSc);
            float c1 = b1[f] - a1 * m1[f];
            s += c1 * W[f * 32 + f2];
        }
        ws[OW_CHL + f2] = s;
        schl[f2] = s;
        float a2 = g2[f2] * rsqrtf(v2[f2] + EPSc);
        ws[OW_A2 + f2] = a2;
        ws[OW_C2 + f2] = b2[f2] + a2 * (bias[f2] - m2[f2]);   // gat bias folded
    }

    // graph: padded in/out lists
    for (int i = tid; i < 64 * MDI; i += TPB) isrcp_i[i] = 0;
    for (int i = tid; i < 64 * MDO; i += TPB) outdst_i[i] = 0;
    if (tid < 64) { inslot[tid] = 0; outslot[tid] = 0; }
    __syncthreads();
    for (int e = tid; e < ne; e += TPB) {
        int s = ei[e], d = ei[ne + e];
        int pi = atomicAdd(&inslot[d], 1);
        if (pi < MDI) isrcp_i[d * MDI + pi] = s;
        int po = atomicAdd(&outslot[s], 1);
        if (po < MDO) outdst_i[s * MDO + po] = d;
    }
    __syncthreads();
    // wes/wed + ces/ced
    if (tid < 128) {
        int k = tid >> 2, h = tid & 3;
        float s1 = 0.f, s2 = 0.f;
        for (int o = 0; o < 8; o++) {
            float wv = sweff[k * 32 + h * 8 + o];
            s1 = fmaf(asrc[h * 8 + o], wv, s1);
            s2 = fmaf(adst[h * 8 + o], wv, s2);
        }
        ws[OW_WES + tid] = s1;
        ws[OW_WES + 128 + tid] = s2;
    }
    if (tid < 4) {
        float s1 = 0.f, s2 = 0.f;
        for (int o = 0; o < 8; o++) {
            float cv = schl[tid * 8 + o];
            s1 = fmaf(asrc[tid * 8 + o], cv, s1);
            s2 = fmaf(adst[tid * 8 + o], cv, s2);
        }
        ws[OW_CES + tid] = s1;
        ws[OW_CES + 4 + tid] = s2;
    }
    // pack graph to bytes
    unsigned char* gb = (unsigned char*)(ws + OW_GRAPH);
    for (int i = tid; i < 64 * MDI; i += TPB) gb[i] = (unsigned char)isrcp_i[i];
    for (int i = tid; i < 64 * MDO; i += TPB) gb[1088 + i] = (unsigned char)outdst_i[i];
    if (tid < 64) {
        gb[1024 + tid] = (unsigned char)(inslot[tid] < MDI ? inslot[tid] : MDI);
        gb[1600 + tid] = (unsigned char)(outslot[tid] < MDO ? outslot[tid] : MDO);
    }
    __syncthreads();
    if (tid == 0) {
        int mi = 0, mo = 0;
        for (int d = 0; d < 64; d++) {
            int a = gb[1024 + d], o = gb[1600 + d];
            mi = a > mi ? a : mi;
            mo = o > mo ? o : mo;
        }
        gb[1664] = (unsigned char)mi;
        gb[1665] = (unsigned char)mo;
    }
}

// ---------------------------------------------------------------------------
// Fused conv1+bn1+GAT + mean(v) + bn2+elu+pool8. wave = head, lane = node.
// Wave-local pipeline (only 2 block barriers):
//   A: es/ed 32-tap convs (regs, x from LDS)
//   B: shfl softmax -> wb[t][v] written to own-wave LDS region
//   C: y[t,c] = sum_v wb[t,v]*x[v,c]  (lane=(t,cgroup), own h; c=39 col = S)
//   D: g[t,h*8+o] = sum_k weff[k,f2]*y[t,t+k] + chl[f2]*S  (lane=(t,o))
//   sync -> epilogue bn2+elu+pool8
// ---------------------------------------------------------------------------
__global__ __launch_bounds__(TPB, 5) void gat_kernel(const float* __restrict__ x,
                                                     const float* __restrict__ wfp,
                                                     const float* __restrict__ chlp,
                                                     const float* __restrict__ wesed,
                                                     const float* __restrict__ cesed,
                                                     const float* __restrict__ a2p,
                                                     const float* __restrict__ c2p,
                                                     const int* __restrict__ graphi,
                                                     float* __restrict__ pout)
{
    __shared__ __align__(16) float sm[L_TOT];

    const int tid  = threadIdx.x;
    const int b    = blockIdx.x / 192;
    const int tile = blockIdx.x % 192;
    const int t0   = tile * 8;

    // ---- stage: x window, weff, wes/wed, chl, graph ----
    for (int idx = tid; idx < 64 * 41; idx += TPB) {
        int v = idx / 41, j = idx % 41;
        float val = 0.f;
        if (j < 39) {
            int t = t0 - 15 + j;
            val = (t >= 0 && t < Tc) ? x[(b * 64 + v) * Tc + t] : 0.f;
        } else if (j == 39) val = 1.0f;
        sm[L_XT + idx] = val;
    }
    for (int idx = tid; idx < 1024; idx += TPB) sm[L_WF + idx] = wfp[idx];
    sm[L_WE + tid] = wesed[tid];
    if (tid < 32) sm[L_CHL + tid] = chlp[tid];
    {
        int* gd = (int*)&sm[L_GR];
        for (int idx = tid; idx < GB_INTS; idx += TPB) gd[idx] = graphi[idx];
    }
    __syncthreads();

    const int h = tid >> 6, v = tid & 63;     // wave = head, lane = node
    const unsigned char* gb = (const unsigned char*)&sm[L_GR];

    // ---- Phase A: es/ed convs (registers) ----
    float aes[8], aed[8];
    {
        const float cesh = cesed[h], cedh = cesed[4 + h];
        const float* xrow = &sm[L_XT + v * 41];
        #pragma unroll
        for (int t = 0; t < 8; t++) { aes[t] = cesh; aed[t] = cedh; }
        float xr[8];
        #pragma unroll
        for (int q = 0; q < 7; q++) xr[q] = xrow[q];
        #pragma unroll
        for (int k = 0; k < 32; k++) {
            xr[(k + 7) & 7] = xrow[k + 7];
            const float wek = sm[L_WE + k * 4 + h];
            const float wdk = sm[L_WE + 128 + k * 4 + h];
            #pragma unroll
            for (int t = 0; t < 8; t++) {
                const float xv = xr[(k + t) & 7];
                aes[t] = fmaf(xv, wek, aes[t]);
                aed[t] = fmaf(xv, wdk, aed[t]);
            }
        }
    }

    // ---- Phase B: shfl softmax (no max-shift: logits O(1), ratio exact) ----
    {
        const int indeg = gb[1024 + v];
        const int mdin  = gb[1664];
        float den[8] = { 0.f,0.f,0.f,0.f,0.f,0.f,0.f,0.f };
        for (int e = 0; e < mdin; e++) {
            const int s = gb[v * MDI + e];
            const float valid = (e < indeg) ? 1.f : 0.f;
            #pragma unroll
            for (int t = 0; t < 8; t++) {
                float ev = __shfl(aes[t], s) + aed[t];
                ev = ev > 0.f ? ev : NSLOPE * ev;
                den[t] += valid * __expf(ev);
            }
        }
        float rden[8];
        #pragma unroll
        for (int t = 0; t < 8; t++) rden[t] = 1.f / den[t];

        const int odeg = gb[1600 + v];
        const int mdo  = gb[1665];
        float wb[8] = { 0.f,0.f,0.f,0.f,0.f,0.f,0.f,0.f };
        for (int j = 0; j < mdo; j++) {
            const int d = gb[1088 + v * MDO + j];
            const float valid = (j < odeg) ? 1.f : 0.f;
            #pragma unroll
            for (int t = 0; t < 8; t++) {
                float ev = aes[t] + __shfl(aed[t], d);
                ev = ev > 0.f ? ev : NSLOPE * ev;
                wb[t] += valid * __expf(ev) * __shfl(rden[t], d);
            }
        }
        #pragma unroll
        for (int t = 0; t < 8; t++) sm[L_WB + h * 520 + t * 65 + v] = wb[t];
    }
    __asm__ volatile("s_waitcnt lgkmcnt(0)" ::: "memory");   // wave-local drain

    // ---- Phase C: y[t,c] = sum_v wb[t,v]*x[v,c]; lane = (t, cgroup) ----
    {
        const int t = v >> 3, cg = v & 7;
        const float* wbrow = &sm[L_WB + h * 520 + t * 65];
        float ya[5] = { 0.f, 0.f, 0.f, 0.f, 0.f };
        for (int vv = 0; vv < 64; vv++) {
            const float wbv = wbrow[vv];
            const float* xv = &sm[L_XT + vv * 41 + cg];
            #pragma unroll
            for (int q = 0; q < 5; q++)
                ya[q] = fmaf(wbv, xv[q * 8], ya[q]);
        }
        float* yrow = &sm[L_Y + h * 328 + t * 41];
        #pragma unroll
        for (int q = 0; q < 5; q++) yrow[cg + q * 8] = ya[q];
    }
    __asm__ volatile("s_waitcnt lgkmcnt(0)" ::: "memory");   // wave-local drain

    // ---- Phase D: g[t, h*8+o] = sum_k weff[k,f2]*y[t,t+k] + chl[f2]*S ----
    {
        const int t = v >> 3, o = v & 7, f2 = h * 8 + o;
        const float* yrow = &sm[L_Y + h * 328 + t * 41];
        float acc = sm[L_CHL + f2] * yrow[39];
        #pragma unroll
        for (int k = 0; k < 32; k++)
            acc = fmaf(sm[L_WF + k * 32 + f2], yrow[t + k], acc);
        sm[L_G + t * 32 + f2] = acc;
    }
    __syncthreads();

    // ---- Epilogue: bn2 + elu + pool8 (block = one pool group) ----
    if (tid < 32) {
        const float a2l = a2p[tid], c2l = c2p[tid];
        float s = 0.f;
        #pragma unroll
        for (int t = 0; t < 8; t++) {
            float gv = sm[L_G + t * 32 + tid] * (1.f / 64.f);
            float y = fmaf(a2l, gv, c2l);
            s += y > 0.f ? y : __expf(y) - 1.f;
        }
        pout[(b * T2c + tile) * 32 + tid] = s * 0.125f;
    }
}

// ---------------------------------------------------------------------------
// conv3(K=16,'same') + bn3 + elu + avgpool(4): p[B,192,32] -> out[B,32,48].
// Self-sufficient: stages w3 transposed into LDS (padded strides), computes
// bn3 affine in-kernel.
// ---------------------------------------------------------------------------
__global__ __launch_bounds__(TPB) void conv3_kernel(const float* __restrict__ pp,
                                                    const float* __restrict__ w3,
                                                    const float* __restrict__ g3,
                                                    const float* __restrict__ b3,
                                                    const float* __restrict__ m3,
                                                    const float* __restrict__ v3,
                                                    float* __restrict__ outp)
{
    __shared__ float w3s[16 * 1057];     // [k]*1057 + [f2i]*33 + f2o
    __shared__ float pl[63 * 32];
    __shared__ float q[48 * 32];
    const int tid = threadIdx.x;
    const int b = blockIdx.x >> 2, cc = blockIdx.x & 3;

    // stage w3 (coalesced float4 reads, bank-spread scattered writes)
    for (int idx4 = tid; idx4 < 4096; idx4 += TPB) {
        const float4 w4 = *(const float4*)(w3 + idx4 * 4);
        const int k0 = (idx4 * 4) & 15, f2i = (idx4 >> 2) & 31, f2o = idx4 >> 7;
        const float wq[4] = { w4.x, w4.y, w4.z, w4.w };
        #pragma unroll
        for (int j = 0; j < 4; j++)
            w3s[(k0 + j) * 1057 + f2i * 33 + f2o] = wq[j];
    }
    for (int idx = tid; idx < 63 * 32; idx += TPB) {
        int r = idx >> 5, f2 = idx & 31;
        int tog = cc * 48 - 7 + r;
        pl[idx] = (tog >= 0 && tog < T2c) ? pp[(b * T2c + tog) * 32 + f2] : 0.f;
    }
    __syncthreads();

    const int f2o = tid & 31, grp = tid >> 5;
    const int tb = grp * 6;
    float acc[6] = { 0.f, 0.f, 0.f, 0.f, 0.f, 0.f };
    for (int f2i = 0; f2i < 32; f2i++) {
        float seg[21];
        #pragma unroll
        for (int r = 0; r < 21; r++) seg[r] = pl[(tb + r) * 32 + f2i];
        #pragma unroll
        for (int k = 0; k < 16; k++) {
            float wv = w3s[k * 1057 + f2i * 33 + f2o];
            #pragma unroll
            for (int j = 0; j < 6; j++)
                acc[j] = fmaf(seg[j + k], wv, acc[j]);
        }
    }
    const float a3 = g3[f2o] * rsqrtf(v3[f2o] + EPSc);
    const float c3 = b3[f2o] - a3 * m3[f2o];
    #pragma unroll
    for (int j = 0; j < 6; j++) {
        float y = fmaf(a3, acc[j], c3);
        y = y > 0.f ? y : __expf(y) - 1.f;
        q[(tb + j) * 32 + f2o] = y;
    }
    __syncthreads();
    for (int idx = tid; idx < 12 * 32; idx += TPB) {
        int t4 = idx >> 5, f2 = idx & 31;
        int r0 = t4 * 4;
        float s = q[r0 * 32 + f2] + q[(r0 + 1) * 32 + f2] +
                  q[(r0 + 2) * 32 + f2] + q[(r0 + 3) * 32 + f2];
        outp[(b * 32 + f2) * 48 + cc * 12 + t4] = s * 0.25f;
    }
}

// ---------------------------------------------------------------------------
extern "C" void kernel_launch(void* const* d_in, const int* in_sizes, int n_in,
                              void* d_out, int out_size, void* d_ws, size_t ws_size,
                              hipStream_t stream)
{
    const float* x    = (const float*)d_in[0];
    const float* c1w  = (const float*)d_in[1];
    const float* g1   = (const float*)d_in[2];
    const float* b1   = (const float*)d_in[3];
    const float* m1   = (const float*)d_in[4];
    const float* v1   = (const float*)d_in[5];
    const float* W    = (const float*)d_in[6];
    const float* asrc = (const float*)d_in[7];
    const float* adst = (const float*)d_in[8];
    const float* bias = (const float*)d_in[9];
    const float* g2   = (const float*)d_in[10];
    const float* b2   = (const float*)d_in[11];
    const float* m2   = (const float*)d_in[12];
    const float* v2   = (const float*)d_in[13];
    const float* w3   = (const float*)d_in[14];
    const float* g3   = (const float*)d_in[15];
    const float* b3   = (const float*)d_in[16];
    const float* m3   = (const float*)d_in[17];
    const float* v3   = (const float*)d_in[18];
    const int*   ei   = (const int*)d_in[19];
    const int    ne   = in_sizes[19] / 2;

    float* ws = (float*)d_ws;

    prep_kernel<<<1, TPB, 0, stream>>>(c1w, g1, b1, m1, v1, W, bias, asrc, adst,
                                       g2, b2, m2, v2, ei, ne, ws);

    gat_kernel<<<Bc * T2c, TPB, 0, stream>>>(x,
                                             ws + OW_WEFF, ws + OW_CHL,
                                             ws + OW_WES, ws + OW_CES,
                                             ws + OW_A2, ws + OW_C2,
                                             (const int*)(ws + OW_GRAPH),
                                             ws + OW_P);

    conv3_kernel<<<Bc * 4, TPB, 0, stream>>>(ws + OW_P, w3, g3, b3, m3, v3,
                                             (float*)d_out);
}